// Round 1
// baseline (488.106 us; speedup 1.0000x reference)
//
#include <hip/hip_runtime.h>

typedef unsigned short u16;
typedef __attribute__((ext_vector_type(8))) short short8;
typedef __attribute__((ext_vector_type(4))) float floatx4;

__device__ __forceinline__ u16 f2bf(float f) {
  unsigned u = __float_as_uint(f);
  u += 0x7fff + ((u >> 16) & 1);   // round-to-nearest-even
  return (u16)(u >> 16);
}

// ---------------- weight transpose fp32(K,N) -> bf16(N,K) ----------------
__global__ __launch_bounds__(256) void wtrans(const float* __restrict__ in,
                                              u16* __restrict__ out, int K, int N) {
  __shared__ float t[32][33];
  const int n0 = blockIdx.x * 32, k0 = blockIdx.y * 32;
  const int tx = threadIdx.x, ty = threadIdx.y;   // 32 x 8
#pragma unroll
  for (int i = 0; i < 32; i += 8)
    t[ty + i][tx] = in[(size_t)(k0 + ty + i) * N + n0 + tx];
  __syncthreads();
#pragma unroll
  for (int i = 0; i < 32; i += 8)
    out[(size_t)(n0 + ty + i) * K + k0 + tx] = f2bf(t[tx][ty + i]);
}

// ---------------- RMSNorm * (1+scale) -> bf16 ----------------
__global__ __launch_bounds__(256) void rmsnorm_mod(const float* __restrict__ x,
                                                   const float* __restrict__ scale,
                                                   u16* __restrict__ out, int D, float eps) {
  const int row = blockIdx.x;
  const float* xr = x + (size_t)row * D;
  float ss = 0.f;
  for (int c = threadIdx.x; c < D; c += 256) { float v = xr[c]; ss += v * v; }
  for (int off = 32; off > 0; off >>= 1) ss += __shfl_down(ss, off);
  __shared__ float red[4];
  if ((threadIdx.x & 63) == 0) red[threadIdx.x >> 6] = ss;
  __syncthreads();
  const float tot = red[0] + red[1] + red[2] + red[3];
  const float r = rsqrtf(tot / (float)D + eps);
  for (int c = threadIdx.x; c < D; c += 256)
    out[(size_t)row * D + c] = f2bf(xr[c] * r * (1.0f + scale[c]));
}

// ---------------- bf16 MFMA GEMM: C(MxN) = A(MxK) * BT(NxK)^T + bias ----------------
// M%128==0, N%128==0, K%32==0. 256 thr = 4 waves in 2x2 of 64x64 subtiles.
__global__ __launch_bounds__(256) void gemm_bf16(const u16* __restrict__ A,
                                                 const u16* __restrict__ BT,
                                                 const float* __restrict__ bias,
                                                 float* __restrict__ C,
                                                 int M, int N, int K) {
  __shared__ __align__(16) u16 As[128][32];
  __shared__ __align__(16) u16 Bs[128][32];
  const int tid = threadIdx.x;
  const int lane = tid & 63, wave = tid >> 6;
  const int bm = blockIdx.y * 128, bn = blockIdx.x * 128;
  const int wm = (wave & 1) * 64, wn = (wave >> 1) * 64;
  const int row16 = lane & 15, quad = lane >> 4;
  const int srow = tid >> 1, scol = (tid & 1) * 16;

  floatx4 acc[4][4] = {};
  const u16* Ag = A + (size_t)(bm + srow) * K + scol;
  const u16* Bg = BT + (size_t)(bn + srow) * K + scol;

  for (int k0 = 0; k0 < K; k0 += 32) {
    const uint4 a0 = *(const uint4*)(Ag + k0);
    const uint4 a1 = *(const uint4*)(Ag + k0 + 8);
    const uint4 b0 = *(const uint4*)(Bg + k0);
    const uint4 b1 = *(const uint4*)(Bg + k0 + 8);
    *(uint4*)&As[srow][scol] = a0;
    *(uint4*)&As[srow][scol + 8] = a1;
    *(uint4*)&Bs[srow][scol] = b0;
    *(uint4*)&Bs[srow][scol + 8] = b1;
    __syncthreads();
    short8 af[4], bf[4];
#pragma unroll
    for (int i = 0; i < 4; i++) {
      af[i] = *(const short8*)&As[wm + i * 16 + row16][quad * 8];
      bf[i] = *(const short8*)&Bs[wn + i * 16 + row16][quad * 8];
    }
#pragma unroll
    for (int mi = 0; mi < 4; mi++)
#pragma unroll
      for (int ni = 0; ni < 4; ni++)
        acc[mi][ni] = __builtin_amdgcn_mfma_f32_16x16x32_bf16(af[mi], bf[ni], acc[mi][ni], 0, 0, 0);
    __syncthreads();
  }
#pragma unroll
  for (int mi = 0; mi < 4; mi++) {
#pragma unroll
    for (int ni = 0; ni < 4; ni++) {
      const int col = bn + wn + ni * 16 + row16;
      const float b = bias[col];
      const int row0 = bm + wm + mi * 16 + quad * 4;
#pragma unroll
      for (int r = 0; r < 4; r++)
        C[(size_t)(row0 + r) * N + col] = acc[mi][ni][r] + b;
    }
  }
}

// ---------------- per-head q/k RMSNorm + RoPE(x only) + qk-scale; emit Q,K,V bf16 (H,S,D) ----------------
__global__ __launch_bounds__(128) void qkv_post(const float* __restrict__ qkvx,
                                                const float* __restrict__ qkvy,
                                                const float* __restrict__ qnwx, const float* __restrict__ knwx,
                                                const float* __restrict__ qnwy, const float* __restrict__ knwy,
                                                const float* __restrict__ rcos, const float* __restrict__ rsin,
                                                u16* __restrict__ Q, u16* __restrict__ Kb, u16* __restrict__ V) {
  const int s = blockIdx.x, h = blockIdx.y, d = threadIdx.x;
  const bool isx = s < 2048;
  const float* base = isx ? (qkvx + (size_t)s * 4608) : (qkvy + (size_t)(s - 2048) * 4608);
  const float q = base[h * 128 + d];
  const float k = base[1536 + h * 128 + d];
  const float v = base[3072 + h * 128 + d];
  __shared__ float redq[2], redk[2];
  float sq = q * q, sk = k * k;
  for (int off = 32; off > 0; off >>= 1) { sq += __shfl_down(sq, off); sk += __shfl_down(sk, off); }
  const int lane = threadIdx.x & 63, w = threadIdx.x >> 6;
  if (lane == 0) { redq[w] = sq; redk[w] = sk; }
  __syncthreads();
  const float rq = rsqrtf((redq[0] + redq[1]) * (1.f / 128.f) + 1e-5f);
  const float rk = rsqrtf((redk[0] + redk[1]) * (1.f / 128.f) + 1e-5f);
  float qn = q * rq * (isx ? qnwx[d] : qnwy[d]);
  float kn = k * rk * (isx ? knwx[d] : knwy[d]);
  if (isx) {
    const int i = d >> 1;
    const float c = rcos[((size_t)s * 12 + h) * 64 + i];
    const float sn = rsin[((size_t)s * 12 + h) * 64 + i];
    const float qo = __shfl_xor(qn, 1);
    const float ko = __shfl_xor(kn, 1);
    qn = (d & 1) ? (qo * sn + qn * c) : (qn * c - qo * sn);
    kn = (d & 1) ? (ko * sn + kn * c) : (kn * c - ko * sn);
  }
  qn *= 0.08838834764831845f;  // 1/sqrt(128) folded into Q
  const size_t o = ((size_t)h * 2304 + s) * 128 + d;
  Q[o] = f2bf(qn);
  Kb[o] = f2bf(kn);
  V[o] = f2bf(v);
}

// ---------------- per-head V (S,D) -> Vt (D,S) ----------------
__global__ __launch_bounds__(256) void vtrans(const u16* __restrict__ V, u16* __restrict__ Vt) {
  __shared__ u16 t[32][33];
  const int h = blockIdx.x, st = blockIdx.y * 32, dt = blockIdx.z * 32;
  const u16* Vh = V + (size_t)h * 2304 * 128;
  u16* Vth = Vt + (size_t)h * 128 * 2304;
  const int tx = threadIdx.x, ty = threadIdx.y;
#pragma unroll
  for (int i = 0; i < 32; i += 8)
    t[ty + i][tx] = Vh[(size_t)(st + ty + i) * 128 + dt + tx];
  __syncthreads();
#pragma unroll
  for (int i = 0; i < 32; i += 8)
    Vth[(size_t)(dt + ty + i) * 2304 + st + tx] = t[tx][ty + i];
}

// ---------------- flash attention, 64 q-rows per block (16/wave), 64-key tiles ----------------
__global__ __launch_bounds__(256) void attn(const u16* __restrict__ Q, const u16* __restrict__ Kb,
                                            const u16* __restrict__ Vt, u16* __restrict__ O) {
  const int h = blockIdx.y;
  const int q0 = blockIdx.x * 64;
  const int tid = threadIdx.x, lane = tid & 63, wave = tid >> 6;
  const int row16 = lane & 15, quad = lane >> 4;
  const u16* Qh = Q + (size_t)h * 2304 * 128;
  const u16* Kh = Kb + (size_t)h * 2304 * 128;
  const u16* Vh = Vt + (size_t)h * 128 * 2304;

  __shared__ __align__(16) u16 Ks[64][136];   // +8 pad: break 256B-stride bank aliasing
  __shared__ __align__(16) u16 Vs[128][72];   // +8 pad
  __shared__ __align__(16) u16 Ps[4][16][72]; // per-wave P round-trip C->A layout

  short8 qf[4];
  {
    const u16* qrow = Qh + (size_t)(q0 + wave * 16 + row16) * 128;
#pragma unroll
    for (int kk = 0; kk < 4; kk++) qf[kk] = *(const short8*)(qrow + kk * 32 + quad * 8);
  }
  floatx4 oacc[8] = {};
  float m_i[4], l_i[4];
#pragma unroll
  for (int r = 0; r < 4; r++) { m_i[r] = -1e30f; l_i[r] = 0.f; }

  const int kr = tid >> 2, ksg = (tid & 3) * 32;
  const int vr = tid >> 1, vsg = (tid & 1) * 32;

  for (int kt = 0; kt < 2304; kt += 64) {
    __syncthreads();
    {
      const uint4* g = (const uint4*)(Kh + (size_t)(kt + kr) * 128 + ksg);
      uint4* l4 = (uint4*)&Ks[kr][ksg];
      l4[0] = g[0]; l4[1] = g[1]; l4[2] = g[2]; l4[3] = g[3];
      const uint4* gv = (const uint4*)(Vh + (size_t)vr * 2304 + kt + vsg);
      uint4* lv = (uint4*)&Vs[vr][vsg];
      lv[0] = gv[0]; lv[1] = gv[1]; lv[2] = gv[2]; lv[3] = gv[3];
    }
    __syncthreads();

    floatx4 sacc[4] = {};
#pragma unroll
    for (int nk = 0; nk < 4; nk++) {
#pragma unroll
      for (int kk = 0; kk < 4; kk++) {
        short8 bfrag = *(const short8*)&Ks[nk * 16 + row16][kk * 32 + quad * 8];
        sacc[nk] = __builtin_amdgcn_mfma_f32_16x16x32_bf16(qf[kk], bfrag, sacc[nk], 0, 0, 0);
      }
    }
    // online softmax per row (row = quad*4 + r)
    float al[4];
#pragma unroll
    for (int r = 0; r < 4; r++) {
      float mx = fmaxf(fmaxf(sacc[0][r], sacc[1][r]), fmaxf(sacc[2][r], sacc[3][r]));
      mx = fmaxf(mx, __shfl_xor(mx, 1));
      mx = fmaxf(mx, __shfl_xor(mx, 2));
      mx = fmaxf(mx, __shfl_xor(mx, 4));
      mx = fmaxf(mx, __shfl_xor(mx, 8));
      const float mnew = fmaxf(m_i[r], mx);
      al[r] = exp2f((m_i[r] - mnew) * 1.4426950408889634f);
      m_i[r] = mnew;
    }
    float ps[4] = {0.f, 0.f, 0.f, 0.f};
#pragma unroll
    for (int nk = 0; nk < 4; nk++) {
#pragma unroll
      for (int r = 0; r < 4; r++) {
        const float p = exp2f((sacc[nk][r] - m_i[r]) * 1.4426950408889634f);
        sacc[nk][r] = p;
        ps[r] += p;
      }
    }
#pragma unroll
    for (int r = 0; r < 4; r++) {
      float s = ps[r];
      s += __shfl_xor(s, 1); s += __shfl_xor(s, 2);
      s += __shfl_xor(s, 4); s += __shfl_xor(s, 8);
      l_i[r] = l_i[r] * al[r] + s;
#pragma unroll
      for (int ni = 0; ni < 8; ni++) oacc[ni][r] *= al[r];
    }
    // P: C-layout -> LDS -> A-layout (per-wave region, no barrier needed)
#pragma unroll
    for (int nk = 0; nk < 4; nk++)
#pragma unroll
      for (int r = 0; r < 4; r++)
        Ps[wave][quad * 4 + r][nk * 16 + row16] = f2bf(sacc[nk][r]);
    short8 pf[2];
#pragma unroll
    for (int kk = 0; kk < 2; kk++)
      pf[kk] = *(const short8*)&Ps[wave][row16][kk * 32 + quad * 8];
#pragma unroll
    for (int ni = 0; ni < 8; ni++) {
#pragma unroll
      for (int kk = 0; kk < 2; kk++) {
        short8 vfrag = *(const short8*)&Vs[ni * 16 + row16][kk * 32 + quad * 8];
        oacc[ni] = __builtin_amdgcn_mfma_f32_16x16x32_bf16(pf[kk], vfrag, oacc[ni], 0, 0, 0);
      }
    }
  }
#pragma unroll
  for (int ni = 0; ni < 8; ni++) {
#pragma unroll
    for (int r = 0; r < 4; r++) {
      const int s = q0 + wave * 16 + quad * 4 + r;
      const int d = ni * 16 + row16;
      O[(size_t)s * 1536 + h * 128 + d] = f2bf(oacc[ni][r] / l_i[r]);
    }
  }
}

// ---------------- launch ----------------
extern "C" void kernel_launch(void* const* d_in, const int* in_sizes, int n_in,
                              void* d_out, int out_size, void* d_ws, size_t ws_size,
                              hipStream_t stream) {
  const float* x        = (const float*)d_in[0];
  const float* y        = (const float*)d_in[1];
  const float* scale_x  = (const float*)d_in[2];
  const float* scale_y  = (const float*)d_in[3];
  const float* rope_cos = (const float*)d_in[4];
  const float* rope_sin = (const float*)d_in[5];
  const float* Wqkv_x   = (const float*)d_in[6];
  const float* bqkv_x   = (const float*)d_in[7];
  const float* Wqkv_y   = (const float*)d_in[8];
  const float* bqkv_y   = (const float*)d_in[9];
  const float* qnwx     = (const float*)d_in[10];
  const float* knwx     = (const float*)d_in[11];
  const float* qnwy     = (const float*)d_in[12];
  const float* knwy     = (const float*)d_in[13];
  const float* Wproj_x  = (const float*)d_in[14];
  const float* bproj_x  = (const float*)d_in[15];
  const float* Wproj_y  = (const float*)d_in[16];
  const float* bproj_y  = (const float*)d_in[17];
  float* out = (float*)d_out;

  char* ws = (char*)d_ws;
  size_t off = 0;
  auto take = [&](size_t bytes) { char* p = ws + off; off += (bytes + 255) & ~(size_t)255; return p; };
  u16* WqkvxT  = (u16*)take((size_t)4608 * 1536 * 2);
  u16* WqkvyT  = (u16*)take((size_t)4608 * 768 * 2);
  u16* WprojxT = (u16*)take((size_t)1536 * 1536 * 2);
  u16* WprojyT = (u16*)take((size_t)768 * 1536 * 2);
  u16* xm      = (u16*)take((size_t)2048 * 1536 * 2);
  u16* ym      = (u16*)take((size_t)256 * 768 * 2);
  float* qkvx  = (float*)take((size_t)2048 * 4608 * 4);
  float* qkvy  = (float*)take((size_t)256 * 4608 * 4);
  u16* Qb      = (u16*)take((size_t)12 * 2304 * 128 * 2);
  u16* Kb      = (u16*)take((size_t)12 * 2304 * 128 * 2);
  u16* Vb      = (u16*)take((size_t)12 * 2304 * 128 * 2);
  u16* Vt      = (u16*)take((size_t)12 * 128 * 2304 * 2);
  u16* attnout = (u16*)take((size_t)2304 * 1536 * 2);

  // weight prep: fp32 (K,N) -> bf16 (N,K)
  wtrans<<<dim3(4608 / 32, 1536 / 32), dim3(32, 8), 0, stream>>>(Wqkv_x, WqkvxT, 1536, 4608);
  wtrans<<<dim3(4608 / 32, 768 / 32), dim3(32, 8), 0, stream>>>(Wqkv_y, WqkvyT, 768, 4608);
  wtrans<<<dim3(1536 / 32, 1536 / 32), dim3(32, 8), 0, stream>>>(Wproj_x, WprojxT, 1536, 1536);
  wtrans<<<dim3(768 / 32, 1536 / 32), dim3(32, 8), 0, stream>>>(Wproj_y, WprojyT, 1536, 768);

  rmsnorm_mod<<<2048, 256, 0, stream>>>(x, scale_x, xm, 1536, 1e-6f);
  rmsnorm_mod<<<256, 256, 0, stream>>>(y, scale_y, ym, 768, 1e-6f);

  gemm_bf16<<<dim3(4608 / 128, 2048 / 128), 256, 0, stream>>>(xm, WqkvxT, bqkv_x, qkvx, 2048, 4608, 1536);
  gemm_bf16<<<dim3(4608 / 128, 256 / 128), 256, 0, stream>>>(ym, WqkvyT, bqkv_y, qkvy, 256, 4608, 768);

  qkv_post<<<dim3(2304, 12), 128, 0, stream>>>(qkvx, qkvy, qnwx, knwx, qnwy, knwy,
                                               rope_cos, rope_sin, Qb, Kb, Vb);
  vtrans<<<dim3(12, 2304 / 32, 128 / 32), dim3(32, 8), 0, stream>>>(Vb, Vt);

  attn<<<dim3(2304 / 64, 12), 256, 0, stream>>>(Qb, Kb, Vt, attnout);

  gemm_bf16<<<dim3(1536 / 128, 2048 / 128), 256, 0, stream>>>(attnout, WprojxT, bproj_x, out, 2048, 1536, 1536);
  gemm_bf16<<<dim3(768 / 128, 256 / 128), 256, 0, stream>>>(attnout + (size_t)2048 * 1536, WprojyT, bproj_y,
                                                            out + (size_t)2048 * 1536, 256, 768, 1536);
  (void)in_sizes; (void)n_in; (void)out_size; (void)ws_size;
}

// Round 2
// 449.484 us; speedup vs baseline: 1.0859x; 1.0859x over previous
//
#include <hip/hip_runtime.h>

typedef unsigned short u16;
typedef __attribute__((ext_vector_type(8))) short short8;
typedef __attribute__((ext_vector_type(4))) short short4v;
typedef __attribute__((ext_vector_type(4))) float floatx4;

__device__ __forceinline__ u16 f2bf(float f) {
  unsigned u = __float_as_uint(f);
  u += 0x7fff + ((u >> 16) & 1);   // round-to-nearest-even
  return (u16)(u >> 16);
}

#define GLD16(g, l) __builtin_amdgcn_global_load_lds( \
    (const __attribute__((address_space(1))) void*)(g), \
    (__attribute__((address_space(3))) void*)(l), 16, 0, 0)

// ---------------- weight transpose fp32(K,N) -> bf16(N,K) ----------------
__global__ __launch_bounds__(256) void wtrans(const float* __restrict__ in,
                                              u16* __restrict__ out, int K, int N) {
  __shared__ float t[32][33];
  const int n0 = blockIdx.x * 32, k0 = blockIdx.y * 32;
  const int tx = threadIdx.x, ty = threadIdx.y;   // 32 x 8
#pragma unroll
  for (int i = 0; i < 32; i += 8)
    t[ty + i][tx] = in[(size_t)(k0 + ty + i) * N + n0 + tx];
  __syncthreads();
#pragma unroll
  for (int i = 0; i < 32; i += 8)
    out[(size_t)(n0 + ty + i) * K + k0 + tx] = f2bf(t[tx][ty + i]);
}

// ---------------- RMSNorm * (1+scale) -> bf16 ----------------
__global__ __launch_bounds__(256) void rmsnorm_mod(const float* __restrict__ x,
                                                   const float* __restrict__ scale,
                                                   u16* __restrict__ out, int D, float eps) {
  const int row = blockIdx.x;
  const float* xr = x + (size_t)row * D;
  float ss = 0.f;
  for (int c = threadIdx.x; c < D; c += 256) { float v = xr[c]; ss += v * v; }
  for (int off = 32; off > 0; off >>= 1) ss += __shfl_down(ss, off);
  __shared__ float red[4];
  if ((threadIdx.x & 63) == 0) red[threadIdx.x >> 6] = ss;
  __syncthreads();
  const float tot = red[0] + red[1] + red[2] + red[3];
  const float r = rsqrtf(tot / (float)D + eps);
  for (int c = threadIdx.x; c < D; c += 256)
    out[(size_t)row * D + c] = f2bf(xr[c] * r * (1.0f + scale[c]));
}

// ---------------- bf16 MFMA GEMM (m97-style global_load_lds staging) ----------------
// C(MxN) = A(MxK) * BT(NxK)^T + bias. M%128==0, N%128==0, K%32==0.
__global__ __launch_bounds__(256) void gemm_bf16(const u16* __restrict__ A,
                                                 const u16* __restrict__ BT,
                                                 const float* __restrict__ bias,
                                                 float* __restrict__ C,
                                                 int M, int N, int K) {
  __shared__ __align__(16) u16 As[128 * 32];
  __shared__ __align__(16) u16 Bs[128 * 32];
  const int tid = threadIdx.x;
  const int lane = tid & 63, wave = tid >> 6;
  const int bm = blockIdx.y * 128, bn = blockIdx.x * 128;
  const int wm = (wave & 1) * 64, wn = (wave >> 1) * 64;
  const int row16 = lane & 15, quad = lane >> 4;

  floatx4 acc[4][4] = {};
  // staging: 8 chunks of 1 KiB each per tile; wave w owns chunks {w, w+4}
  const int r0 = lane >> 2, c4 = (lane & 3) * 8;
  const u16* Ag0 = A + (size_t)(bm + wave * 16 + r0) * K + c4;
  const u16* Ag1 = A + (size_t)(bm + (wave + 4) * 16 + r0) * K + c4;
  const u16* Bg0 = BT + (size_t)(bn + wave * 16 + r0) * K + c4;
  const u16* Bg1 = BT + (size_t)(bn + (wave + 4) * 16 + r0) * K + c4;
  u16* As0 = As + wave * 512; u16* As1 = As + (wave + 4) * 512;
  u16* Bs0 = Bs + wave * 512; u16* Bs1 = Bs + (wave + 4) * 512;

  for (int k0 = 0; k0 < K; k0 += 32) {
    GLD16(Ag0 + k0, As0);
    GLD16(Ag1 + k0, As1);
    GLD16(Bg0 + k0, Bs0);
    GLD16(Bg1 + k0, Bs1);
    __syncthreads();
    short8 af[4], bf[4];
#pragma unroll
    for (int i = 0; i < 4; i++) {
      af[i] = *(const short8*)&As[(wm + i * 16 + row16) * 32 + quad * 8];
      bf[i] = *(const short8*)&Bs[(wn + i * 16 + row16) * 32 + quad * 8];
    }
#pragma unroll
    for (int mi = 0; mi < 4; mi++)
#pragma unroll
      for (int ni = 0; ni < 4; ni++)
        acc[mi][ni] = __builtin_amdgcn_mfma_f32_16x16x32_bf16(af[mi], bf[ni], acc[mi][ni], 0, 0, 0);
    __syncthreads();
  }
#pragma unroll
  for (int mi = 0; mi < 4; mi++) {
#pragma unroll
    for (int ni = 0; ni < 4; ni++) {
      const int col = bn + wn + ni * 16 + row16;
      const float b = bias[col];
      const int row0 = bm + wm + mi * 16 + quad * 4;
#pragma unroll
      for (int r = 0; r < 4; r++)
        C[(size_t)(row0 + r) * N + col] = acc[mi][ni][r] + b;
    }
  }
}

// ---------------- per-head q/k RMSNorm + RoPE(x only); emit Q,K,V bf16 (H,S,D) ----------------
// Q is folded with (1/sqrt(D)) * log2(e) so attention works in exp2 domain.
__global__ __launch_bounds__(128) void qkv_post(const float* __restrict__ qkvx,
                                                const float* __restrict__ qkvy,
                                                const float* __restrict__ qnwx, const float* __restrict__ knwx,
                                                const float* __restrict__ qnwy, const float* __restrict__ knwy,
                                                const float* __restrict__ rcos, const float* __restrict__ rsin,
                                                u16* __restrict__ Q, u16* __restrict__ Kb, u16* __restrict__ V) {
  const int s = blockIdx.x, h = blockIdx.y, d = threadIdx.x;
  const bool isx = s < 2048;
  const float* base = isx ? (qkvx + (size_t)s * 4608) : (qkvy + (size_t)(s - 2048) * 4608);
  const float q = base[h * 128 + d];
  const float k = base[1536 + h * 128 + d];
  const float v = base[3072 + h * 128 + d];
  __shared__ float redq[2], redk[2];
  float sq = q * q, sk = k * k;
  for (int off = 32; off > 0; off >>= 1) { sq += __shfl_down(sq, off); sk += __shfl_down(sk, off); }
  const int lane = threadIdx.x & 63, w = threadIdx.x >> 6;
  if (lane == 0) { redq[w] = sq; redk[w] = sk; }
  __syncthreads();
  const float rq = rsqrtf((redq[0] + redq[1]) * (1.f / 128.f) + 1e-5f);
  const float rk = rsqrtf((redk[0] + redk[1]) * (1.f / 128.f) + 1e-5f);
  float qn = q * rq * (isx ? qnwx[d] : qnwy[d]);
  float kn = k * rk * (isx ? knwx[d] : knwy[d]);
  if (isx) {
    const int i = d >> 1;
    const float c = rcos[((size_t)s * 12 + h) * 64 + i];
    const float sn = rsin[((size_t)s * 12 + h) * 64 + i];
    const float qo = __shfl_xor(qn, 1);
    const float ko = __shfl_xor(kn, 1);
    qn = (d & 1) ? (qo * sn + qn * c) : (qn * c - qo * sn);
    kn = (d & 1) ? (ko * sn + kn * c) : (kn * c - ko * sn);
  }
  qn *= 0.12751737942f;  // (1/sqrt(128)) * log2(e)
  const size_t o = ((size_t)h * 2304 + s) * 128 + d;
  Q[o] = f2bf(qn);
  Kb[o] = f2bf(kn);
  V[o] = f2bf(v);
}

// ---------------- per-head V (S,D) -> Vt (D,S) ----------------
__global__ __launch_bounds__(256) void vtrans(const u16* __restrict__ V, u16* __restrict__ Vt) {
  __shared__ u16 t[32][33];
  const int h = blockIdx.x, st = blockIdx.y * 32, dt = blockIdx.z * 32;
  const u16* Vh = V + (size_t)h * 2304 * 128;
  u16* Vth = Vt + (size_t)h * 128 * 2304;
  const int tx = threadIdx.x, ty = threadIdx.y;
#pragma unroll
  for (int i = 0; i < 32; i += 8)
    t[ty + i][tx] = Vh[(size_t)(st + ty + i) * 128 + dt + tx];
  __syncthreads();
#pragma unroll
  for (int i = 0; i < 32; i += 8)
    Vth[(size_t)(dt + ty + i) * 2304 + st + tx] = t[tx][ty + i];
}

// ---------------- flash attention, transposed scores + split-K ----------------
// Grid (36 q-tiles, 12 heads, 2 splits). 64 q/block (16/wave), 64-key tiles.
// S^T = K*Q^T so each lane owns ONE q-column: softmax is in-lane + 2 shuffles.
// Writes UNNORMALIZED O partials + per-row m,l (exp2 domain) for the combine.
__global__ __launch_bounds__(256) void attn(const u16* __restrict__ Q, const u16* __restrict__ Kb,
                                            const u16* __restrict__ Vt,
                                            float* __restrict__ Opart,
                                            float* __restrict__ Mp, float* __restrict__ Lp) {
  const int h = blockIdx.y, split = blockIdx.z;
  const int q0 = blockIdx.x * 64;
  const int tid = threadIdx.x, lane = tid & 63, wave = tid >> 6;
  const int row16 = lane & 15, quad = lane >> 4;
  const u16* Qh = Q + (size_t)h * 2304 * 128;
  const u16* Kh = Kb + (size_t)h * 2304 * 128;
  const u16* Vh = Vt + (size_t)h * 128 * 2304;

  __shared__ __align__(16) u16 Ks[64][136];
  __shared__ __align__(16) u16 Vs[128][72];
  __shared__ __align__(16) u16 Ps[4][16][72];  // per-wave P^T round-trip (A-layout)

  short8 qf[4];  // B-operand fragments: B[k=d][n=q] read from Q rows
  {
    const u16* qrow = Qh + (size_t)(q0 + wave * 16 + row16) * 128;
#pragma unroll
    for (int kk = 0; kk < 4; kk++) qf[kk] = *(const short8*)(qrow + kk * 32 + quad * 8);
  }
  floatx4 oacc[8] = {};
  float m_i = -1e30f, l_i = 0.f;   // per-lane: this lane's q-column (= row16)

  const int kr = tid >> 2, ksg = (tid & 3) * 32;
  const int vr = tid >> 1, vsg = (tid & 1) * 32;
  const int kbeg = split * 1152, kend = kbeg + 1152;

  for (int kt = kbeg; kt < kend; kt += 64) {
    __syncthreads();
    {
      const uint4* g = (const uint4*)(Kh + (size_t)(kt + kr) * 128 + ksg);
      uint4* l4 = (uint4*)&Ks[kr][ksg];
      l4[0] = g[0]; l4[1] = g[1]; l4[2] = g[2]; l4[3] = g[3];
      const uint4* gv = (const uint4*)(Vh + (size_t)vr * 2304 + kt + vsg);
      uint4* lv = (uint4*)&Vs[vr][vsg];
      lv[0] = gv[0]; lv[1] = gv[1]; lv[2] = gv[2]; lv[3] = gv[3];
    }
    __syncthreads();

    // S^T tiles: sacc[mk] covers keys mk*16+quad*4+r, q-col = row16
    floatx4 sacc[4] = {};
#pragma unroll
    for (int mk = 0; mk < 4; mk++) {
#pragma unroll
      for (int kk = 0; kk < 4; kk++) {
        short8 kfrag = *(const short8*)&Ks[mk * 16 + row16][kk * 32 + quad * 8];
        sacc[mk] = __builtin_amdgcn_mfma_f32_16x16x32_bf16(kfrag, qf[kk], sacc[mk], 0, 0, 0);
      }
    }
    // online softmax: 16 in-lane scores, cross-quad via 2 shuffles
    float mx = sacc[0][0];
#pragma unroll
    for (int mk = 0; mk < 4; mk++)
#pragma unroll
      for (int r = 0; r < 4; r++) mx = fmaxf(mx, sacc[mk][r]);
    mx = fmaxf(mx, __shfl_xor(mx, 16));
    mx = fmaxf(mx, __shfl_xor(mx, 32));
    const float mnew = fmaxf(m_i, mx);
    const float alpha = exp2f(m_i - mnew);
    m_i = mnew;
    float s = 0.f;
#pragma unroll
    for (int mk = 0; mk < 4; mk++) {
#pragma unroll
      for (int r = 0; r < 4; r++) {
        const float p = exp2f(sacc[mk][r] - mnew);
        sacc[mk][r] = p;
        s += p;
      }
    }
    s += __shfl_xor(s, 16);
    s += __shfl_xor(s, 32);
    l_i = l_i * alpha + s;

    // P^T -> per-wave LDS in A-layout: Ps[wave][q][key]
#pragma unroll
    for (int mk = 0; mk < 4; mk++) {
      short4v pk;
      pk[0] = (short)f2bf(sacc[mk][0]); pk[1] = (short)f2bf(sacc[mk][1]);
      pk[2] = (short)f2bf(sacc[mk][2]); pk[3] = (short)f2bf(sacc[mk][3]);
      *(short4v*)&Ps[wave][row16][mk * 16 + quad * 4] = pk;
    }
    // rescale O accumulators (row = q = quad*4+r; alpha lives at lane q)
    const float a0 = __shfl(alpha, quad * 4 + 0);
    const float a1 = __shfl(alpha, quad * 4 + 1);
    const float a2 = __shfl(alpha, quad * 4 + 2);
    const float a3 = __shfl(alpha, quad * 4 + 3);
#pragma unroll
    for (int nd = 0; nd < 8; nd++) {
      oacc[nd][0] *= a0; oacc[nd][1] *= a1; oacc[nd][2] *= a2; oacc[nd][3] *= a3;
    }
    const short8 pf0 = *(const short8*)&Ps[wave][row16][quad * 8];
    const short8 pf1 = *(const short8*)&Ps[wave][row16][32 + quad * 8];
#pragma unroll
    for (int nd = 0; nd < 8; nd++) {
      const short8 vf0 = *(const short8*)&Vs[nd * 16 + row16][quad * 8];
      const short8 vf1 = *(const short8*)&Vs[nd * 16 + row16][32 + quad * 8];
      oacc[nd] = __builtin_amdgcn_mfma_f32_16x16x32_bf16(pf0, vf0, oacc[nd], 0, 0, 0);
      oacc[nd] = __builtin_amdgcn_mfma_f32_16x16x32_bf16(pf1, vf1, oacc[nd], 0, 0, 0);
    }
  }
  const size_t base = (size_t)(split * 12 + h) * 2304 + q0 + wave * 16;
#pragma unroll
  for (int nd = 0; nd < 8; nd++)
#pragma unroll
    for (int r = 0; r < 4; r++)
      Opart[(base + quad * 4 + r) * 128 + nd * 16 + row16] = oacc[nd][r];
  if (lane < 16) { Mp[base + lane] = m_i; Lp[base + lane] = l_i; }
}

// ---------------- combine 2 splits -> attnout bf16 (S, 1536) ----------------
__global__ __launch_bounds__(256) void attn_combine(const float* __restrict__ Opart,
                                                    const float* __restrict__ Mp,
                                                    const float* __restrict__ Lp,
                                                    u16* __restrict__ attnout) {
  const int idx = blockIdx.x * 256 + threadIdx.x;   // one per 4 output elems
  const int dd = (idx & 31) * 4;
  const int hq = idx >> 5;
  const int h = hq % 12, q = hq / 12;
  const size_t b0 = (size_t)h * 2304 + q;
  const size_t b1 = (size_t)(12 + h) * 2304 + q;
  const float m0 = Mp[b0], m1 = Mp[b1];
  const float l0 = Lp[b0], l1 = Lp[b1];
  const float m = fmaxf(m0, m1);
  const float w0 = exp2f(m0 - m), w1 = exp2f(m1 - m);
  const float inv = 1.0f / (l0 * w0 + l1 * w1);
  const float4 o0 = *(const float4*)&Opart[b0 * 128 + dd];
  const float4 o1 = *(const float4*)&Opart[b1 * 128 + dd];
  short4v out;
  out[0] = (short)f2bf((o0.x * w0 + o1.x * w1) * inv);
  out[1] = (short)f2bf((o0.y * w0 + o1.y * w1) * inv);
  out[2] = (short)f2bf((o0.z * w0 + o1.z * w1) * inv);
  out[3] = (short)f2bf((o0.w * w0 + o1.w * w1) * inv);
  *(short4v*)&attnout[(size_t)idx * 4] = out;
}

// ---------------- launch ----------------
extern "C" void kernel_launch(void* const* d_in, const int* in_sizes, int n_in,
                              void* d_out, int out_size, void* d_ws, size_t ws_size,
                              hipStream_t stream) {
  const float* x        = (const float*)d_in[0];
  const float* y        = (const float*)d_in[1];
  const float* scale_x  = (const float*)d_in[2];
  const float* scale_y  = (const float*)d_in[3];
  const float* rope_cos = (const float*)d_in[4];
  const float* rope_sin = (const float*)d_in[5];
  const float* Wqkv_x   = (const float*)d_in[6];
  const float* bqkv_x   = (const float*)d_in[7];
  const float* Wqkv_y   = (const float*)d_in[8];
  const float* bqkv_y   = (const float*)d_in[9];
  const float* qnwx     = (const float*)d_in[10];
  const float* knwx     = (const float*)d_in[11];
  const float* qnwy     = (const float*)d_in[12];
  const float* knwy     = (const float*)d_in[13];
  const float* Wproj_x  = (const float*)d_in[14];
  const float* bproj_x  = (const float*)d_in[15];
  const float* Wproj_y  = (const float*)d_in[16];
  const float* bproj_y  = (const float*)d_in[17];
  float* out = (float*)d_out;

  char* ws = (char*)d_ws;
  size_t off = 0;
  auto take = [&](size_t bytes) { char* p = ws + off; off += (bytes + 255) & ~(size_t)255; return p; };
  u16* WqkvxT  = (u16*)take((size_t)4608 * 1536 * 2);
  u16* WqkvyT  = (u16*)take((size_t)4608 * 768 * 2);
  u16* WprojxT = (u16*)take((size_t)1536 * 1536 * 2);
  u16* WprojyT = (u16*)take((size_t)768 * 1536 * 2);
  u16* xm      = (u16*)take((size_t)2048 * 1536 * 2);
  u16* ym      = (u16*)take((size_t)256 * 768 * 2);
  float* qkvx  = (float*)take((size_t)2048 * 4608 * 4);
  float* qkvy  = (float*)take((size_t)256 * 4608 * 4);
  u16* Qb      = (u16*)take((size_t)12 * 2304 * 128 * 2);
  u16* Kb      = (u16*)take((size_t)12 * 2304 * 128 * 2);
  u16* Vb      = (u16*)take((size_t)12 * 2304 * 128 * 2);
  u16* Vt      = (u16*)take((size_t)12 * 128 * 2304 * 2);
  u16* attnout = (u16*)take((size_t)2304 * 1536 * 2);
  float* Opart = (float*)take((size_t)2 * 12 * 2304 * 128 * 4);
  float* Mp    = (float*)take((size_t)2 * 12 * 2304 * 4);
  float* Lp    = (float*)take((size_t)2 * 12 * 2304 * 4);

  wtrans<<<dim3(4608 / 32, 1536 / 32), dim3(32, 8), 0, stream>>>(Wqkv_x, WqkvxT, 1536, 4608);
  wtrans<<<dim3(4608 / 32, 768 / 32), dim3(32, 8), 0, stream>>>(Wqkv_y, WqkvyT, 768, 4608);
  wtrans<<<dim3(1536 / 32, 1536 / 32), dim3(32, 8), 0, stream>>>(Wproj_x, WprojxT, 1536, 1536);
  wtrans<<<dim3(768 / 32, 1536 / 32), dim3(32, 8), 0, stream>>>(Wproj_y, WprojyT, 1536, 768);

  rmsnorm_mod<<<2048, 256, 0, stream>>>(x, scale_x, xm, 1536, 1e-6f);
  rmsnorm_mod<<<256, 256, 0, stream>>>(y, scale_y, ym, 768, 1e-6f);

  gemm_bf16<<<dim3(4608 / 128, 2048 / 128), 256, 0, stream>>>(xm, WqkvxT, bqkv_x, qkvx, 2048, 4608, 1536);
  gemm_bf16<<<dim3(4608 / 128, 256 / 128), 256, 0, stream>>>(ym, WqkvyT, bqkv_y, qkvy, 256, 4608, 768);

  qkv_post<<<dim3(2304, 12), 128, 0, stream>>>(qkvx, qkvy, qnwx, knwx, qnwy, knwy,
                                               rope_cos, rope_sin, Qb, Kb, Vb);
  vtrans<<<dim3(12, 2304 / 32, 128 / 32), dim3(32, 8), 0, stream>>>(Vb, Vt);

  attn<<<dim3(2304 / 64, 12, 2), 256, 0, stream>>>(Qb, Kb, Vt, Opart, Mp, Lp);
  attn_combine<<<(2304 * 1536 / 4) / 256, 256, 0, stream>>>(Opart, Mp, Lp, attnout);

  gemm_bf16<<<dim3(1536 / 128, 2048 / 128), 256, 0, stream>>>(attnout, WprojxT, bproj_x, out, 2048, 1536, 1536);
  gemm_bf16<<<dim3(768 / 128, 256 / 128), 256, 0, stream>>>(attnout + (size_t)2048 * 1536, WprojyT, bproj_y,
                                                            out + (size_t)2048 * 1536, 256, 768, 1536);
  (void)in_sizes; (void)n_in; (void)out_size; (void)ws_size;
}

// Round 3
// 421.755 us; speedup vs baseline: 1.1573x; 1.0657x over previous
//
#include <hip/hip_runtime.h>

typedef unsigned short u16;
typedef __attribute__((ext_vector_type(8))) short short8;
typedef __attribute__((ext_vector_type(4))) short short4v;
typedef __attribute__((ext_vector_type(4))) float floatx4;

__device__ __forceinline__ u16 f2bf(float f) {
  unsigned u = __float_as_uint(f);
  u += 0x7fff + ((u >> 16) & 1);   // round-to-nearest-even
  return (u16)(u >> 16);
}

#define GLD16(g, l) __builtin_amdgcn_global_load_lds( \
    (const __attribute__((address_space(1))) void*)(g), \
    (__attribute__((address_space(3))) void*)(l), 16, 0, 0)

// ---------------- weight transpose fp32(K,N) -> bf16(N,K) ----------------
__global__ __launch_bounds__(256) void wtrans(const float* __restrict__ in,
                                              u16* __restrict__ out, int K, int N) {
  __shared__ float t[32][33];
  const int n0 = blockIdx.x * 32, k0 = blockIdx.y * 32;
  const int tx = threadIdx.x, ty = threadIdx.y;   // 32 x 8
#pragma unroll
  for (int i = 0; i < 32; i += 8)
    t[ty + i][tx] = in[(size_t)(k0 + ty + i) * N + n0 + tx];
  __syncthreads();
#pragma unroll
  for (int i = 0; i < 32; i += 8)
    out[(size_t)(n0 + ty + i) * K + k0 + tx] = f2bf(t[tx][ty + i]);
}

// ---------------- RMSNorm * (1+scale) -> bf16 ----------------
__global__ __launch_bounds__(256) void rmsnorm_mod(const float* __restrict__ x,
                                                   const float* __restrict__ scale,
                                                   u16* __restrict__ out, int D, float eps) {
  const int row = blockIdx.x;
  const float* xr = x + (size_t)row * D;
  float ss = 0.f;
  for (int c = threadIdx.x; c < D; c += 256) { float v = xr[c]; ss += v * v; }
  for (int off = 32; off > 0; off >>= 1) ss += __shfl_down(ss, off);
  __shared__ float red[4];
  if ((threadIdx.x & 63) == 0) red[threadIdx.x >> 6] = ss;
  __syncthreads();
  const float tot = red[0] + red[1] + red[2] + red[3];
  const float r = rsqrtf(tot / (float)D + eps);
  for (int c = threadIdx.x; c < D; c += 256)
    out[(size_t)row * D + c] = f2bf(xr[c] * r * (1.0f + scale[c]));
}

// ---------------- bf16 MFMA GEMM (m97-style global_load_lds staging) ----------------
// C(MxN) = A(MxK) * BT(NxK)^T + bias. M%128==0, N%128==0, K%32==0.
__global__ __launch_bounds__(256) void gemm_bf16(const u16* __restrict__ A,
                                                 const u16* __restrict__ BT,
                                                 const float* __restrict__ bias,
                                                 float* __restrict__ C,
                                                 int M, int N, int K) {
  __shared__ __align__(16) u16 As[128 * 32];
  __shared__ __align__(16) u16 Bs[128 * 32];
  const int tid = threadIdx.x;
  const int lane = tid & 63, wave = tid >> 6;
  const int bm = blockIdx.y * 128, bn = blockIdx.x * 128;
  const int wm = (wave & 1) * 64, wn = (wave >> 1) * 64;
  const int row16 = lane & 15, quad = lane >> 4;

  floatx4 acc[4][4] = {};
  const int r0 = lane >> 2, c4 = (lane & 3) * 8;
  const u16* Ag0 = A + (size_t)(bm + wave * 16 + r0) * K + c4;
  const u16* Ag1 = A + (size_t)(bm + (wave + 4) * 16 + r0) * K + c4;
  const u16* Bg0 = BT + (size_t)(bn + wave * 16 + r0) * K + c4;
  const u16* Bg1 = BT + (size_t)(bn + (wave + 4) * 16 + r0) * K + c4;
  u16* As0 = As + wave * 512; u16* As1 = As + (wave + 4) * 512;
  u16* Bs0 = Bs + wave * 512; u16* Bs1 = Bs + (wave + 4) * 512;

  for (int k0 = 0; k0 < K; k0 += 32) {
    GLD16(Ag0 + k0, As0);
    GLD16(Ag1 + k0, As1);
    GLD16(Bg0 + k0, Bs0);
    GLD16(Bg1 + k0, Bs1);
    __syncthreads();
    short8 af[4], bf[4];
#pragma unroll
    for (int i = 0; i < 4; i++) {
      af[i] = *(const short8*)&As[(wm + i * 16 + row16) * 32 + quad * 8];
      bf[i] = *(const short8*)&Bs[(wn + i * 16 + row16) * 32 + quad * 8];
    }
#pragma unroll
    for (int mi = 0; mi < 4; mi++)
#pragma unroll
      for (int ni = 0; ni < 4; ni++)
        acc[mi][ni] = __builtin_amdgcn_mfma_f32_16x16x32_bf16(af[mi], bf[ni], acc[mi][ni], 0, 0, 0);
    __syncthreads();
  }
#pragma unroll
  for (int mi = 0; mi < 4; mi++) {
#pragma unroll
    for (int ni = 0; ni < 4; ni++) {
      const int col = bn + wn + ni * 16 + row16;
      const float b = bias[col];
      const int row0 = bm + wm + mi * 16 + quad * 4;
#pragma unroll
      for (int r = 0; r < 4; r++)
        C[(size_t)(row0 + r) * N + col] = acc[mi][ni][r] + b;
    }
  }
}

// ---------------- per-head q/k RMSNorm + RoPE(x only); emit Q,K,V bf16 (H,S,D) ----------------
// Q is folded with (1/sqrt(D)) * log2(e) so attention works in exp2 domain.
__global__ __launch_bounds__(128) void qkv_post(const float* __restrict__ qkvx,
                                                const float* __restrict__ qkvy,
                                                const float* __restrict__ qnwx, const float* __restrict__ knwx,
                                                const float* __restrict__ qnwy, const float* __restrict__ knwy,
                                                const float* __restrict__ rcos, const float* __restrict__ rsin,
                                                u16* __restrict__ Q, u16* __restrict__ Kb, u16* __restrict__ V) {
  const int s = blockIdx.x, h = blockIdx.y, d = threadIdx.x;
  const bool isx = s < 2048;
  const float* base = isx ? (qkvx + (size_t)s * 4608) : (qkvy + (size_t)(s - 2048) * 4608);
  const float q = base[h * 128 + d];
  const float k = base[1536 + h * 128 + d];
  const float v = base[3072 + h * 128 + d];
  __shared__ float redq[2], redk[2];
  float sq = q * q, sk = k * k;
  for (int off = 32; off > 0; off >>= 1) { sq += __shfl_down(sq, off); sk += __shfl_down(sk, off); }
  const int lane = threadIdx.x & 63, w = threadIdx.x >> 6;
  if (lane == 0) { redq[w] = sq; redk[w] = sk; }
  __syncthreads();
  const float rq = rsqrtf((redq[0] + redq[1]) * (1.f / 128.f) + 1e-5f);
  const float rk = rsqrtf((redk[0] + redk[1]) * (1.f / 128.f) + 1e-5f);
  float qn = q * rq * (isx ? qnwx[d] : qnwy[d]);
  float kn = k * rk * (isx ? knwx[d] : knwy[d]);
  if (isx) {
    const int i = d >> 1;
    const float c = rcos[((size_t)s * 12 + h) * 64 + i];
    const float sn = rsin[((size_t)s * 12 + h) * 64 + i];
    const float qo = __shfl_xor(qn, 1);
    const float ko = __shfl_xor(kn, 1);
    qn = (d & 1) ? (qo * sn + qn * c) : (qn * c - qo * sn);
    kn = (d & 1) ? (ko * sn + kn * c) : (kn * c - ko * sn);
  }
  qn *= 0.12751737942f;  // (1/sqrt(128)) * log2(e)
  const size_t o = ((size_t)h * 2304 + s) * 128 + d;
  Q[o] = f2bf(qn);
  Kb[o] = f2bf(kn);
  V[o] = f2bf(v);
}

// ---------------- per-head V (S,D) -> Vt (D,S) ----------------
__global__ __launch_bounds__(256) void vtrans(const u16* __restrict__ V, u16* __restrict__ Vt) {
  __shared__ u16 t[32][33];
  const int h = blockIdx.x, st = blockIdx.y * 32, dt = blockIdx.z * 32;
  const u16* Vh = V + (size_t)h * 2304 * 128;
  u16* Vth = Vt + (size_t)h * 128 * 2304;
  const int tx = threadIdx.x, ty = threadIdx.y;
#pragma unroll
  for (int i = 0; i < 32; i += 8)
    t[ty + i][tx] = Vh[(size_t)(st + ty + i) * 128 + dt + tx];
  __syncthreads();
#pragma unroll
  for (int i = 0; i < 32; i += 8)
    Vth[(size_t)(dt + ty + i) * 2304 + st + tx] = t[tx][ty + i];
}

// ---------------- flash attention: GLD16 swizzled staging, transposed scores, 4-way split-K ------
// Grid (36 q-tiles, 12 heads, 4 splits). 64 q/block (16/wave), 64-key tiles, 576 keys/split.
// LDS layouts (16B chunk position = chunk ^ (row&7)) are conflict-free for all b128 reads,
// and GLD16 DMA staging has no LDS write conflicts by construction.
__global__ __launch_bounds__(256) void attn(const u16* __restrict__ Q, const u16* __restrict__ Kb,
                                            const u16* __restrict__ Vt,
                                            float* __restrict__ Opart,
                                            float* __restrict__ Mp, float* __restrict__ Lp) {
  const int h = blockIdx.y, split = blockIdx.z;
  const int q0 = blockIdx.x * 64;
  const int tid = threadIdx.x, lane = tid & 63, wave = tid >> 6;
  const int row16 = lane & 15, quad = lane >> 4;
  const u16* Qh = Q + (size_t)h * 2304 * 128;
  const u16* Kh = Kb + (size_t)h * 2304 * 128;
  const u16* Vh = Vt + (size_t)h * 128 * 2304;

  __shared__ __align__(16) u16 Ks[64 * 128];   // swizzled: 64 key-rows x 16 chunks
  __shared__ __align__(16) u16 Vs[128 * 64];   // swizzled: 128 d-rows x 8 chunks
  __shared__ __align__(16) u16 Ps[4][16 * 64]; // swizzled per-wave P (16 q x 64 keys)

  short8 qf[4];
  {
    const u16* qrow = Qh + (size_t)(q0 + wave * 16 + row16) * 128;
#pragma unroll
    for (int kk = 0; kk < 4; kk++) qf[kk] = *(const short8*)(qrow + kk * 32 + quad * 8);
  }
  floatx4 oacc[8] = {};
  float m_i = -1e30f, l_i = 0.f;   // per-lane: q-column = row16

  // staging source addresses (swizzle on global side; LDS dest is wave base + lane*16)
  int krow[4], kcol[4], vrow[4], vcol[4];
#pragma unroll
  for (int i = 0; i < 4; i++) {
    const int j = i * 4 + wave;
    krow[i] = j * 4 + (lane >> 4);            // key row 0..63
    kcol[i] = ((lane & 15) ^ (krow[i] & 7)) * 8;
    vrow[i] = j * 8 + (lane >> 3);            // d row 0..127
    vcol[i] = ((lane & 7) ^ (vrow[i] & 7)) * 8;
  }
  const int sw = row16 & 7;
  const int kbeg = split * 576, kend = kbeg + 576;

  for (int kt = kbeg; kt < kend; kt += 64) {
    __syncthreads();
#pragma unroll
    for (int i = 0; i < 4; i++) {
      GLD16(Kh + (size_t)(kt + krow[i]) * 128 + kcol[i], Ks + (i * 4 + wave) * 512);
      GLD16(Vh + (size_t)vrow[i] * 2304 + kt + vcol[i], Vs + (i * 4 + wave) * 512);
    }
    __syncthreads();

    // S^T: sacc[mk] covers keys mk*16+quad*4+r, q-col = row16
    floatx4 sacc[4] = {};
#pragma unroll
    for (int mk = 0; mk < 4; mk++) {
#pragma unroll
      for (int kk = 0; kk < 4; kk++) {
        const int c = (4 * kk + quad) ^ sw;
        const short8 kfrag = *(const short8*)&Ks[(mk * 16 + row16) * 128 + c * 8];
        sacc[mk] = __builtin_amdgcn_mfma_f32_16x16x32_bf16(kfrag, qf[kk], sacc[mk], 0, 0, 0);
      }
    }
    // online softmax: 16 in-lane scores + 2 cross-quad shuffles
    float mx = sacc[0][0];
#pragma unroll
    for (int mk = 0; mk < 4; mk++)
#pragma unroll
      for (int r = 0; r < 4; r++) mx = fmaxf(mx, sacc[mk][r]);
    mx = fmaxf(mx, __shfl_xor(mx, 16));
    mx = fmaxf(mx, __shfl_xor(mx, 32));
    const float mnew = fmaxf(m_i, mx);
    const float alpha = exp2f(m_i - mnew);
    m_i = mnew;
    float s = 0.f;
#pragma unroll
    for (int mk = 0; mk < 4; mk++) {
#pragma unroll
      for (int r = 0; r < 4; r++) {
        const float p = exp2f(sacc[mk][r] - mnew);
        sacc[mk][r] = p;
        s += p;
      }
    }
    s += __shfl_xor(s, 16);
    s += __shfl_xor(s, 32);
    l_i = l_i * alpha + s;

    // P -> per-wave swizzled LDS (C-layout in, A-layout out; conflict-free both ways)
#pragma unroll
    for (int mk = 0; mk < 4; mk++) {
      const int subp = (4 * mk + quad) ^ (sw << 1);
      short4v pk;
      pk[0] = (short)f2bf(sacc[mk][0]); pk[1] = (short)f2bf(sacc[mk][1]);
      pk[2] = (short)f2bf(sacc[mk][2]); pk[3] = (short)f2bf(sacc[mk][3]);
      *(short4v*)&Ps[wave][row16 * 64 + subp * 4] = pk;
    }
    // rescale O (row q = quad*4+r; alpha lives at lane q)
    const float a0 = __shfl(alpha, quad * 4 + 0);
    const float a1 = __shfl(alpha, quad * 4 + 1);
    const float a2 = __shfl(alpha, quad * 4 + 2);
    const float a3 = __shfl(alpha, quad * 4 + 3);
#pragma unroll
    for (int nd = 0; nd < 8; nd++) {
      oacc[nd][0] *= a0; oacc[nd][1] *= a1; oacc[nd][2] *= a2; oacc[nd][3] *= a3;
    }
    const int pc0 = quad ^ sw, pc1 = (4 + quad) ^ sw;
    const short8 pf0 = *(const short8*)&Ps[wave][row16 * 64 + pc0 * 8];
    const short8 pf1 = *(const short8*)&Ps[wave][row16 * 64 + pc1 * 8];
#pragma unroll
    for (int nd = 0; nd < 8; nd++) {
      const short8 vf0 = *(const short8*)&Vs[(nd * 16 + row16) * 64 + pc0 * 8];
      const short8 vf1 = *(const short8*)&Vs[(nd * 16 + row16) * 64 + pc1 * 8];
      oacc[nd] = __builtin_amdgcn_mfma_f32_16x16x32_bf16(pf0, vf0, oacc[nd], 0, 0, 0);
      oacc[nd] = __builtin_amdgcn_mfma_f32_16x16x32_bf16(pf1, vf1, oacc[nd], 0, 0, 0);
    }
  }
  const size_t base = (size_t)(split * 12 + h) * 2304 + q0 + wave * 16;
#pragma unroll
  for (int nd = 0; nd < 8; nd++)
#pragma unroll
    for (int r = 0; r < 4; r++)
      Opart[(base + quad * 4 + r) * 128 + nd * 16 + row16] = oacc[nd][r];
  if (lane < 16) { Mp[base + lane] = m_i; Lp[base + lane] = l_i; }
}

// ---------------- combine 4 splits -> attnout bf16 (S, 1536) ----------------
__global__ __launch_bounds__(256) void attn_combine(const float* __restrict__ Opart,
                                                    const float* __restrict__ Mp,
                                                    const float* __restrict__ Lp,
                                                    u16* __restrict__ attnout) {
  const int idx = blockIdx.x * 256 + threadIdx.x;   // one per 4 output elems
  const int dd = (idx & 31) * 4;
  const int hq = idx >> 5;
  const int h = hq % 12, q = hq / 12;
  size_t b[4]; float ms[4], ls[4];
  float m = -1e30f;
#pragma unroll
  for (int s = 0; s < 4; s++) {
    b[s] = (size_t)(s * 12 + h) * 2304 + q;
    ms[s] = Mp[b[s]]; ls[s] = Lp[b[s]];
    m = fmaxf(m, ms[s]);
  }
  float w[4], denom = 0.f;
#pragma unroll
  for (int s = 0; s < 4; s++) { w[s] = exp2f(ms[s] - m); denom += ls[s] * w[s]; }
  const float inv = 1.0f / denom;
  float ox = 0.f, oy = 0.f, oz = 0.f, ow = 0.f;
#pragma unroll
  for (int s = 0; s < 4; s++) {
    const float4 o = *(const float4*)&Opart[b[s] * 128 + dd];
    ox += o.x * w[s]; oy += o.y * w[s]; oz += o.z * w[s]; ow += o.w * w[s];
  }
  short4v out;
  out[0] = (short)f2bf(ox * inv);
  out[1] = (short)f2bf(oy * inv);
  out[2] = (short)f2bf(oz * inv);
  out[3] = (short)f2bf(ow * inv);
  *(short4v*)&attnout[(size_t)idx * 4] = out;
}

// ---------------- launch ----------------
extern "C" void kernel_launch(void* const* d_in, const int* in_sizes, int n_in,
                              void* d_out, int out_size, void* d_ws, size_t ws_size,
                              hipStream_t stream) {
  const float* x        = (const float*)d_in[0];
  const float* y        = (const float*)d_in[1];
  const float* scale_x  = (const float*)d_in[2];
  const float* scale_y  = (const float*)d_in[3];
  const float* rope_cos = (const float*)d_in[4];
  const float* rope_sin = (const float*)d_in[5];
  const float* Wqkv_x   = (const float*)d_in[6];
  const float* bqkv_x   = (const float*)d_in[7];
  const float* Wqkv_y   = (const float*)d_in[8];
  const float* bqkv_y   = (const float*)d_in[9];
  const float* qnwx     = (const float*)d_in[10];
  const float* knwx     = (const float*)d_in[11];
  const float* qnwy     = (const float*)d_in[12];
  const float* knwy     = (const float*)d_in[13];
  const float* Wproj_x  = (const float*)d_in[14];
  const float* bproj_x  = (const float*)d_in[15];
  const float* Wproj_y  = (const float*)d_in[16];
  const float* bproj_y  = (const float*)d_in[17];
  float* out = (float*)d_out;

  char* ws = (char*)d_ws;
  size_t off = 0;
  auto take = [&](size_t bytes) { char* p = ws + off; off += (bytes + 255) & ~(size_t)255; return p; };
  u16* WqkvxT  = (u16*)take((size_t)4608 * 1536 * 2);
  u16* WqkvyT  = (u16*)take((size_t)4608 * 768 * 2);
  u16* WprojxT = (u16*)take((size_t)1536 * 1536 * 2);
  u16* WprojyT = (u16*)take((size_t)768 * 1536 * 2);
  u16* xm      = (u16*)take((size_t)2048 * 1536 * 2);
  u16* ym      = (u16*)take((size_t)256 * 768 * 2);
  float* qkvx  = (float*)take((size_t)2048 * 4608 * 4);
  float* qkvy  = (float*)take((size_t)256 * 4608 * 4);
  u16* Qb      = (u16*)take((size_t)12 * 2304 * 128 * 2);
  u16* Kb      = (u16*)take((size_t)12 * 2304 * 128 * 2);
  u16* Vb      = (u16*)take((size_t)12 * 2304 * 128 * 2);
  u16* Vt      = (u16*)take((size_t)12 * 128 * 2304 * 2);
  u16* attnout = (u16*)take((size_t)2304 * 1536 * 2);
  float* Opart = (float*)take((size_t)4 * 12 * 2304 * 128 * 4);
  float* Mp    = (float*)take((size_t)4 * 12 * 2304 * 4);
  float* Lp    = (float*)take((size_t)4 * 12 * 2304 * 4);

  wtrans<<<dim3(4608 / 32, 1536 / 32), dim3(32, 8), 0, stream>>>(Wqkv_x, WqkvxT, 1536, 4608);
  wtrans<<<dim3(4608 / 32, 768 / 32), dim3(32, 8), 0, stream>>>(Wqkv_y, WqkvyT, 768, 4608);
  wtrans<<<dim3(1536 / 32, 1536 / 32), dim3(32, 8), 0, stream>>>(Wproj_x, WprojxT, 1536, 1536);
  wtrans<<<dim3(768 / 32, 1536 / 32), dim3(32, 8), 0, stream>>>(Wproj_y, WprojyT, 1536, 768);

  rmsnorm_mod<<<2048, 256, 0, stream>>>(x, scale_x, xm, 1536, 1e-6f);
  rmsnorm_mod<<<256, 256, 0, stream>>>(y, scale_y, ym, 768, 1e-6f);

  gemm_bf16<<<dim3(4608 / 128, 2048 / 128), 256, 0, stream>>>(xm, WqkvxT, bqkv_x, qkvx, 2048, 4608, 1536);
  gemm_bf16<<<dim3(4608 / 128, 256 / 128), 256, 0, stream>>>(ym, WqkvyT, bqkv_y, qkvy, 256, 4608, 768);

  qkv_post<<<dim3(2304, 12), 128, 0, stream>>>(qkvx, qkvy, qnwx, knwx, qnwy, knwy,
                                               rope_cos, rope_sin, Qb, Kb, Vb);
  vtrans<<<dim3(12, 2304 / 32, 128 / 32), dim3(32, 8), 0, stream>>>(Vb, Vt);

  attn<<<dim3(2304 / 64, 12, 4), 256, 0, stream>>>(Qb, Kb, Vt, Opart, Mp, Lp);
  attn_combine<<<(2304 * 1536 / 4) / 256, 256, 0, stream>>>(Opart, Mp, Lp, attnout);

  gemm_bf16<<<dim3(1536 / 128, 2048 / 128), 256, 0, stream>>>(attnout, WprojxT, bproj_x, out, 2048, 1536, 1536);
  gemm_bf16<<<dim3(768 / 128, 256 / 128), 256, 0, stream>>>(attnout + (size_t)2048 * 1536, WprojyT, bproj_y,
                                                            out + (size_t)2048 * 1536, 256, 768, 1536);
  (void)in_sizes; (void)n_in; (void)out_size; (void)ws_size;
}

// Round 4
// 396.280 us; speedup vs baseline: 1.2317x; 1.0643x over previous
//
#include <hip/hip_runtime.h>

typedef unsigned short u16;
typedef __attribute__((ext_vector_type(8))) short short8;
typedef __attribute__((ext_vector_type(4))) short short4v;
typedef __attribute__((ext_vector_type(4))) float floatx4;

__device__ __forceinline__ u16 f2bf(float f) {
  unsigned u = __float_as_uint(f);
  u += 0x7fff + ((u >> 16) & 1);   // round-to-nearest-even
  return (u16)(u >> 16);
}
__device__ __forceinline__ float bf2f(u16 v) {
  return __uint_as_float(((unsigned)v) << 16);
}

#define GLD16(g, l) __builtin_amdgcn_global_load_lds( \
    (const __attribute__((address_space(1))) void*)(g), \
    (__attribute__((address_space(3))) void*)(l), 16, 0, 0)

// ---------------- all 4 weight transposes fp32(K,N) -> bf16(N,K), one launch ----------------
__global__ __launch_bounds__(256) void wtrans_all(const float* __restrict__ W0, u16* __restrict__ T0,
                                                  const float* __restrict__ W1, u16* __restrict__ T1,
                                                  const float* __restrict__ W2, u16* __restrict__ T2,
                                                  const float* __restrict__ W3, u16* __restrict__ T3) {
  const float* in; u16* out; int K, N;
  switch (blockIdx.z) {
    case 0: in = W0; out = T0; K = 1536; N = 4608; break;
    case 1: in = W1; out = T1; K = 768;  N = 4608; break;
    case 2: in = W2; out = T2; K = 1536; N = 1536; break;
    default: in = W3; out = T3; K = 1536; N = 768; break;
  }
  const int n0 = blockIdx.x * 32, k0 = blockIdx.y * 32;
  if (n0 >= N || k0 >= K) return;
  __shared__ float t[32][33];
  const int tx = threadIdx.x, ty = threadIdx.y;   // 32 x 8
#pragma unroll
  for (int i = 0; i < 32; i += 8)
    t[ty + i][tx] = in[(size_t)(k0 + ty + i) * N + n0 + tx];
  __syncthreads();
#pragma unroll
  for (int i = 0; i < 32; i += 8)
    out[(size_t)(n0 + ty + i) * K + k0 + tx] = f2bf(t[tx][ty + i]);
}

// ---------------- RMSNorm * (1+scale) -> bf16, x and y in one launch ----------------
__global__ __launch_bounds__(256) void rmsnorm_both(const float* __restrict__ x,
                                                    const float* __restrict__ scale_x,
                                                    const float* __restrict__ y,
                                                    const float* __restrict__ scale_y,
                                                    u16* __restrict__ xm, u16* __restrict__ ym) {
  const int row = blockIdx.x;
  const float* xr; const float* sc; u16* dst; int D;
  if (row < 2048) { D = 1536; xr = x + (size_t)row * D; sc = scale_x; dst = xm + (size_t)row * D; }
  else { D = 768; xr = y + (size_t)(row - 2048) * D; sc = scale_y; dst = ym + (size_t)(row - 2048) * D; }
  float ss = 0.f;
  for (int c = threadIdx.x; c < D; c += 256) { float v = xr[c]; ss += v * v; }
  for (int off = 32; off > 0; off >>= 1) ss += __shfl_down(ss, off);
  __shared__ float red[4];
  if ((threadIdx.x & 63) == 0) red[threadIdx.x >> 6] = ss;
  __syncthreads();
  const float tot = red[0] + red[1] + red[2] + red[3];
  const float r = rsqrtf(tot / (float)D + 1e-6f);
  for (int c = threadIdx.x; c < D; c += 256)
    dst[c] = f2bf(xr[c] * r * (1.0f + sc[c]));
}

// ---------------- bf16 MFMA GEMM (global_load_lds staging), fp32 or bf16 output ----------------
// C(MxN) = A(MxK) * BT(NxK)^T + bias. M%128==0, N%128==0, K%32==0.
template <bool BOUT>
__global__ __launch_bounds__(256) void gemm_bf16(const u16* __restrict__ A,
                                                 const u16* __restrict__ BT,
                                                 const float* __restrict__ bias,
                                                 void* __restrict__ Cout,
                                                 int M, int N, int K) {
  __shared__ __align__(16) u16 As[128 * 32];
  __shared__ __align__(16) u16 Bs[128 * 32];
  const int tid = threadIdx.x;
  const int lane = tid & 63, wave = tid >> 6;
  const int bm = blockIdx.y * 128, bn = blockIdx.x * 128;
  const int wm = (wave & 1) * 64, wn = (wave >> 1) * 64;
  const int row16 = lane & 15, quad = lane >> 4;

  floatx4 acc[4][4] = {};
  const int r0 = lane >> 2, c4 = (lane & 3) * 8;
  const u16* Ag0 = A + (size_t)(bm + wave * 16 + r0) * K + c4;
  const u16* Ag1 = A + (size_t)(bm + (wave + 4) * 16 + r0) * K + c4;
  const u16* Bg0 = BT + (size_t)(bn + wave * 16 + r0) * K + c4;
  const u16* Bg1 = BT + (size_t)(bn + (wave + 4) * 16 + r0) * K + c4;
  u16* As0 = As + wave * 512; u16* As1 = As + (wave + 4) * 512;
  u16* Bs0 = Bs + wave * 512; u16* Bs1 = Bs + (wave + 4) * 512;

  for (int k0 = 0; k0 < K; k0 += 32) {
    GLD16(Ag0 + k0, As0);
    GLD16(Ag1 + k0, As1);
    GLD16(Bg0 + k0, Bs0);
    GLD16(Bg1 + k0, Bs1);
    __syncthreads();
    short8 af[4], bf[4];
#pragma unroll
    for (int i = 0; i < 4; i++) {
      af[i] = *(const short8*)&As[(wm + i * 16 + row16) * 32 + quad * 8];
      bf[i] = *(const short8*)&Bs[(wn + i * 16 + row16) * 32 + quad * 8];
    }
#pragma unroll
    for (int mi = 0; mi < 4; mi++)
#pragma unroll
      for (int ni = 0; ni < 4; ni++)
        acc[mi][ni] = __builtin_amdgcn_mfma_f32_16x16x32_bf16(af[mi], bf[ni], acc[mi][ni], 0, 0, 0);
    __syncthreads();
  }
#pragma unroll
  for (int mi = 0; mi < 4; mi++) {
#pragma unroll
    for (int ni = 0; ni < 4; ni++) {
      const int col = bn + wn + ni * 16 + row16;
      const float b = bias[col];
      const int row0 = bm + wm + mi * 16 + quad * 4;
#pragma unroll
      for (int r = 0; r < 4; r++) {
        const float v = acc[mi][ni][r] + b;
        if constexpr (BOUT)
          ((u16*)Cout)[(size_t)(row0 + r) * N + col] = f2bf(v);
        else
          ((float*)Cout)[(size_t)(row0 + r) * N + col] = v;
      }
    }
  }
}

// ---------------- per-head q/k RMSNorm + RoPE(x only); emit Q,K,V bf16 (H,S,D) ----------------
// Q folded with (1/sqrt(D)) * log2(e) so attention works in exp2 domain.
__global__ __launch_bounds__(128) void qkv_post(const u16* __restrict__ qkvx,
                                                const u16* __restrict__ qkvy,
                                                const float* __restrict__ qnwx, const float* __restrict__ knwx,
                                                const float* __restrict__ qnwy, const float* __restrict__ knwy,
                                                const float* __restrict__ rcos, const float* __restrict__ rsin,
                                                u16* __restrict__ Q, u16* __restrict__ Kb, u16* __restrict__ V) {
  const int s = blockIdx.x, h = blockIdx.y, d = threadIdx.x;
  const bool isx = s < 2048;
  const u16* base = isx ? (qkvx + (size_t)s * 4608) : (qkvy + (size_t)(s - 2048) * 4608);
  const float q = bf2f(base[h * 128 + d]);
  const float k = bf2f(base[1536 + h * 128 + d]);
  const u16 v = base[3072 + h * 128 + d];
  __shared__ float redq[2], redk[2];
  float sq = q * q, sk = k * k;
  for (int off = 32; off > 0; off >>= 1) { sq += __shfl_down(sq, off); sk += __shfl_down(sk, off); }
  const int lane = threadIdx.x & 63, w = threadIdx.x >> 6;
  if (lane == 0) { redq[w] = sq; redk[w] = sk; }
  __syncthreads();
  const float rq = rsqrtf((redq[0] + redq[1]) * (1.f / 128.f) + 1e-5f);
  const float rk = rsqrtf((redk[0] + redk[1]) * (1.f / 128.f) + 1e-5f);
  float qn = q * rq * (isx ? qnwx[d] : qnwy[d]);
  float kn = k * rk * (isx ? knwx[d] : knwy[d]);
  if (isx) {
    const int i = d >> 1;
    const float c = rcos[((size_t)s * 12 + h) * 64 + i];
    const float sn = rsin[((size_t)s * 12 + h) * 64 + i];
    const float qo = __shfl_xor(qn, 1);
    const float ko = __shfl_xor(kn, 1);
    qn = (d & 1) ? (qo * sn + qn * c) : (qn * c - qo * sn);
    kn = (d & 1) ? (ko * sn + kn * c) : (kn * c - ko * sn);
  }
  qn *= 0.12751737942f;  // (1/sqrt(128)) * log2(e)
  const size_t o = ((size_t)h * 2304 + s) * 128 + d;
  Q[o] = f2bf(qn);
  Kb[o] = f2bf(kn);
  V[o] = v;
}

// ---------------- per-head V (S,D) -> Vt (D,S) ----------------
__global__ __launch_bounds__(256) void vtrans(const u16* __restrict__ V, u16* __restrict__ Vt) {
  __shared__ u16 t[32][33];
  const int h = blockIdx.x, st = blockIdx.y * 32, dt = blockIdx.z * 32;
  const u16* Vh = V + (size_t)h * 2304 * 128;
  u16* Vth = Vt + (size_t)h * 128 * 2304;
  const int tx = threadIdx.x, ty = threadIdx.y;
#pragma unroll
  for (int i = 0; i < 32; i += 8)
    t[ty + i][tx] = Vh[(size_t)(st + ty + i) * 128 + dt + tx];
  __syncthreads();
#pragma unroll
  for (int i = 0; i < 32; i += 8)
    Vth[(size_t)(dt + ty + i) * 2304 + st + tx] = t[tx][ty + i];
}

// ---------------- flash attention: GLD16 swizzled staging, transposed scores, 4-way split-K ------
// Grid (36 q-tiles, 12 heads, 4 splits). 64 q/block (16/wave), 64-key tiles, 576 keys/split.
// LDS 40KB x 4 blocks = 160KB/CU exactly; launch_bounds(256,4) requests 4-block residency.
__global__ __launch_bounds__(256, 4) void attn(const u16* __restrict__ Q, const u16* __restrict__ Kb,
                                               const u16* __restrict__ Vt,
                                               float* __restrict__ Opart,
                                               float* __restrict__ Mp, float* __restrict__ Lp) {
  const int h = blockIdx.y, split = blockIdx.z;
  const int q0 = blockIdx.x * 64;
  const int tid = threadIdx.x, lane = tid & 63, wave = tid >> 6;
  const int row16 = lane & 15, quad = lane >> 4;
  const u16* Qh = Q + (size_t)h * 2304 * 128;
  const u16* Kh = Kb + (size_t)h * 2304 * 128;
  const u16* Vh = Vt + (size_t)h * 128 * 2304;

  __shared__ __align__(16) u16 Ks[64 * 128];   // swizzled: 64 key-rows x 16 chunks
  __shared__ __align__(16) u16 Vs[128 * 64];   // swizzled: 128 d-rows x 8 chunks
  __shared__ __align__(16) u16 Ps[4][16 * 64]; // swizzled per-wave P (16 q x 64 keys)

  short8 qf[4];
  {
    const u16* qrow = Qh + (size_t)(q0 + wave * 16 + row16) * 128;
#pragma unroll
    for (int kk = 0; kk < 4; kk++) qf[kk] = *(const short8*)(qrow + kk * 32 + quad * 8);
  }
  floatx4 oacc[8] = {};
  float m_i = -1e30f, l_i = 0.f;   // per-lane: q-column = row16

  int krow[4], kcol[4], vrow[4], vcol[4];
#pragma unroll
  for (int i = 0; i < 4; i++) {
    const int j = i * 4 + wave;
    krow[i] = j * 4 + (lane >> 4);            // key row 0..63
    kcol[i] = ((lane & 15) ^ (krow[i] & 7)) * 8;
    vrow[i] = j * 8 + (lane >> 3);            // d row 0..127
    vcol[i] = ((lane & 7) ^ (vrow[i] & 7)) * 8;
  }
  const int sw = row16 & 7;
  const int kbeg = split * 576, kend = kbeg + 576;

  for (int kt = kbeg; kt < kend; kt += 64) {
    __syncthreads();
#pragma unroll
    for (int i = 0; i < 4; i++) {
      GLD16(Kh + (size_t)(kt + krow[i]) * 128 + kcol[i], Ks + (i * 4 + wave) * 512);
      GLD16(Vh + (size_t)vrow[i] * 2304 + kt + vcol[i], Vs + (i * 4 + wave) * 512);
    }
    __syncthreads();

    // S^T: sacc[mk] covers keys mk*16+quad*4+r, q-col = row16
    floatx4 sacc[4] = {};
#pragma unroll
    for (int mk = 0; mk < 4; mk++) {
#pragma unroll
      for (int kk = 0; kk < 4; kk++) {
        const int c = (4 * kk + quad) ^ sw;
        const short8 kfrag = *(const short8*)&Ks[(mk * 16 + row16) * 128 + c * 8];
        sacc[mk] = __builtin_amdgcn_mfma_f32_16x16x32_bf16(kfrag, qf[kk], sacc[mk], 0, 0, 0);
      }
    }
    // online softmax: 16 in-lane scores + 2 cross-quad shuffles
    float mx = sacc[0][0];
#pragma unroll
    for (int mk = 0; mk < 4; mk++)
#pragma unroll
      for (int r = 0; r < 4; r++) mx = fmaxf(mx, sacc[mk][r]);
    mx = fmaxf(mx, __shfl_xor(mx, 16));
    mx = fmaxf(mx, __shfl_xor(mx, 32));
    const float mnew = fmaxf(m_i, mx);
    // wave-uniform skip: rescale only when some lane's max moved
    if (__any(mnew > m_i)) {
      const float alpha = exp2f(m_i - mnew);
      m_i = mnew;
      const float a0 = __shfl(alpha, quad * 4 + 0);
      const float a1 = __shfl(alpha, quad * 4 + 1);
      const float a2 = __shfl(alpha, quad * 4 + 2);
      const float a3 = __shfl(alpha, quad * 4 + 3);
#pragma unroll
      for (int nd = 0; nd < 8; nd++) {
        oacc[nd][0] *= a0; oacc[nd][1] *= a1; oacc[nd][2] *= a2; oacc[nd][3] *= a3;
      }
      l_i *= alpha;
    }
    float s = 0.f;
#pragma unroll
    for (int mk = 0; mk < 4; mk++) {
#pragma unroll
      for (int r = 0; r < 4; r++) {
        const float p = exp2f(sacc[mk][r] - m_i);
        sacc[mk][r] = p;
        s += p;
      }
    }
    s += __shfl_xor(s, 16);
    s += __shfl_xor(s, 32);
    l_i += s;

    // P -> per-wave swizzled LDS (C-layout in, A-layout out; conflict-free both ways)
#pragma unroll
    for (int mk = 0; mk < 4; mk++) {
      const int subp = (4 * mk + quad) ^ (sw << 1);
      short4v pk;
      pk[0] = (short)f2bf(sacc[mk][0]); pk[1] = (short)f2bf(sacc[mk][1]);
      pk[2] = (short)f2bf(sacc[mk][2]); pk[3] = (short)f2bf(sacc[mk][3]);
      *(short4v*)&Ps[wave][row16 * 64 + subp * 4] = pk;
    }
    const int pc0 = quad ^ sw, pc1 = (4 + quad) ^ sw;
    const short8 pf0 = *(const short8*)&Ps[wave][row16 * 64 + pc0 * 8];
    const short8 pf1 = *(const short8*)&Ps[wave][row16 * 64 + pc1 * 8];
#pragma unroll
    for (int nd = 0; nd < 8; nd++) {
      const short8 vf0 = *(const short8*)&Vs[(nd * 16 + row16) * 64 + pc0 * 8];
      const short8 vf1 = *(const short8*)&Vs[(nd * 16 + row16) * 64 + pc1 * 8];
      oacc[nd] = __builtin_amdgcn_mfma_f32_16x16x32_bf16(pf0, vf0, oacc[nd], 0, 0, 0);
      oacc[nd] = __builtin_amdgcn_mfma_f32_16x16x32_bf16(pf1, vf1, oacc[nd], 0, 0, 0);
    }
  }
  const size_t base = (size_t)(split * 12 + h) * 2304 + q0 + wave * 16;
#pragma unroll
  for (int nd = 0; nd < 8; nd++)
#pragma unroll
    for (int r = 0; r < 4; r++)
      Opart[(base + quad * 4 + r) * 128 + nd * 16 + row16] = oacc[nd][r];
  if (lane < 16) { Mp[base + lane] = m_i; Lp[base + lane] = l_i; }
}

// ---------------- combine 4 splits -> attnout bf16 (S, 1536) ----------------
__global__ __launch_bounds__(256) void attn_combine(const float* __restrict__ Opart,
                                                    const float* __restrict__ Mp,
                                                    const float* __restrict__ Lp,
                                                    u16* __restrict__ attnout) {
  const int idx = blockIdx.x * 256 + threadIdx.x;   // one per 4 output elems
  const int dd = (idx & 31) * 4;
  const int hq = idx >> 5;
  const int h = hq % 12, q = hq / 12;
  size_t b[4]; float ms[4], ls[4];
  float m = -1e30f;
#pragma unroll
  for (int s = 0; s < 4; s++) {
    b[s] = (size_t)(s * 12 + h) * 2304 + q;
    ms[s] = Mp[b[s]]; ls[s] = Lp[b[s]];
    m = fmaxf(m, ms[s]);
  }
  float w[4], denom = 0.f;
#pragma unroll
  for (int s = 0; s < 4; s++) { w[s] = exp2f(ms[s] - m); denom += ls[s] * w[s]; }
  const float inv = 1.0f / denom;
  float ox = 0.f, oy = 0.f, oz = 0.f, ow = 0.f;
#pragma unroll
  for (int s = 0; s < 4; s++) {
    const float4 o = *(const float4*)&Opart[b[s] * 128 + dd];
    ox += o.x * w[s]; oy += o.y * w[s]; oz += o.z * w[s]; ow += o.w * w[s];
  }
  short4v out;
  out[0] = (short)f2bf(ox * inv);
  out[1] = (short)f2bf(oy * inv);
  out[2] = (short)f2bf(oz * inv);
  out[3] = (short)f2bf(ow * inv);
  *(short4v*)&attnout[(size_t)idx * 4] = out;
}

// ---------------- launch ----------------
extern "C" void kernel_launch(void* const* d_in, const int* in_sizes, int n_in,
                              void* d_out, int out_size, void* d_ws, size_t ws_size,
                              hipStream_t stream) {
  const float* x        = (const float*)d_in[0];
  const float* y        = (const float*)d_in[1];
  const float* scale_x  = (const float*)d_in[2];
  const float* scale_y  = (const float*)d_in[3];
  const float* rope_cos = (const float*)d_in[4];
  const float* rope_sin = (const float*)d_in[5];
  const float* Wqkv_x   = (const float*)d_in[6];
  const float* bqkv_x   = (const float*)d_in[7];
  const float* Wqkv_y   = (const float*)d_in[8];
  const float* bqkv_y   = (const float*)d_in[9];
  const float* qnwx     = (const float*)d_in[10];
  const float* knwx     = (const float*)d_in[11];
  const float* qnwy     = (const float*)d_in[12];
  const float* knwy     = (const float*)d_in[13];
  const float* Wproj_x  = (const float*)d_in[14];
  const float* bproj_x  = (const float*)d_in[15];
  const float* Wproj_y  = (const float*)d_in[16];
  const float* bproj_y  = (const float*)d_in[17];
  float* out = (float*)d_out;

  char* ws = (char*)d_ws;
  size_t off = 0;
  auto take = [&](size_t bytes) { char* p = ws + off; off += (bytes + 255) & ~(size_t)255; return p; };
  u16* WqkvxT  = (u16*)take((size_t)4608 * 1536 * 2);
  u16* WqkvyT  = (u16*)take((size_t)4608 * 768 * 2);
  u16* WprojxT = (u16*)take((size_t)1536 * 1536 * 2);
  u16* WprojyT = (u16*)take((size_t)768 * 1536 * 2);
  u16* xm      = (u16*)take((size_t)2048 * 1536 * 2);
  u16* ym      = (u16*)take((size_t)256 * 768 * 2);
  u16* qkvx    = (u16*)take((size_t)2048 * 4608 * 2);
  u16* qkvy    = (u16*)take((size_t)256 * 4608 * 2);
  u16* Qb      = (u16*)take((size_t)12 * 2304 * 128 * 2);
  u16* Kb      = (u16*)take((size_t)12 * 2304 * 128 * 2);
  u16* Vb      = (u16*)take((size_t)12 * 2304 * 128 * 2);
  u16* Vt      = (u16*)take((size_t)12 * 128 * 2304 * 2);
  u16* attnout = (u16*)take((size_t)2304 * 1536 * 2);
  float* Opart = (float*)take((size_t)4 * 12 * 2304 * 128 * 4);
  float* Mp    = (float*)take((size_t)4 * 12 * 2304 * 4);
  float* Lp    = (float*)take((size_t)4 * 12 * 2304 * 4);

  wtrans_all<<<dim3(144, 48, 4), dim3(32, 8), 0, stream>>>(Wqkv_x, WqkvxT, Wqkv_y, WqkvyT,
                                                           Wproj_x, WprojxT, Wproj_y, WprojyT);
  rmsnorm_both<<<2304, 256, 0, stream>>>(x, scale_x, y, scale_y, xm, ym);

  gemm_bf16<true><<<dim3(4608 / 128, 2048 / 128), 256, 0, stream>>>(xm, WqkvxT, bqkv_x, qkvx, 2048, 4608, 1536);
  gemm_bf16<true><<<dim3(4608 / 128, 256 / 128), 256, 0, stream>>>(ym, WqkvyT, bqkv_y, qkvy, 256, 4608, 768);

  qkv_post<<<dim3(2304, 12), 128, 0, stream>>>(qkvx, qkvy, qnwx, knwx, qnwy, knwy,
                                               rope_cos, rope_sin, Qb, Kb, Vb);
  vtrans<<<dim3(12, 2304 / 32, 128 / 32), dim3(32, 8), 0, stream>>>(Vb, Vt);

  attn<<<dim3(2304 / 64, 12, 4), 256, 0, stream>>>(Qb, Kb, Vt, Opart, Mp, Lp);
  attn_combine<<<(2304 * 1536 / 4) / 256, 256, 0, stream>>>(Opart, Mp, Lp, attnout);

  gemm_bf16<false><<<dim3(1536 / 128, 2048 / 128), 256, 0, stream>>>(attnout, WprojxT, bproj_x, out, 2048, 1536, 1536);
  gemm_bf16<false><<<dim3(768 / 128, 256 / 128), 256, 0, stream>>>(attnout + (size_t)2048 * 1536, WprojyT, bproj_y,
                                                                   out + (size_t)2048 * 1536, 256, 768, 1536);
  (void)in_sizes; (void)n_in; (void)out_size; (void)ws_size;
}

// Round 5
// 327.703 us; speedup vs baseline: 1.4895x; 1.2093x over previous
//
#include <hip/hip_runtime.h>

typedef unsigned short u16;
typedef __attribute__((ext_vector_type(8))) short short8;
typedef __attribute__((ext_vector_type(4))) short short4v;
typedef __attribute__((ext_vector_type(4))) float floatx4;

// round-half-up bf16 (1 add + 1 shr); max error 0.5 ulp like RTNE (ties round up)
__device__ __forceinline__ u16 f2bf(float f) {
  return (u16)((__float_as_uint(f) + 0x8000u) >> 16);
}
__device__ __forceinline__ float bf2f(u16 v) {
  return __uint_as_float(((unsigned)v) << 16);
}
// pack two floats -> two bf16 in one u32: [hi16(b), hi16(a)]
__device__ __forceinline__ unsigned pack_bf2(float a, float b) {
  const unsigned ua = __float_as_uint(a) + 0x8000u;
  const unsigned ub = __float_as_uint(b) + 0x8000u;
  return __builtin_amdgcn_perm(ub, ua, 0x07060302);  // bytes: ub[3],ub[2],ua[3],ua[2]
}

#define GLD16(g, l) __builtin_amdgcn_global_load_lds( \
    (const __attribute__((address_space(1))) void*)(g), \
    (__attribute__((address_space(3))) void*)(l), 16, 0, 0)

// ---------------- prep: 4 weight transposes + rmsnorm(x,y), one launch ----------------
// z<4: transpose fp32(K,N)->bf16(N,K).  z==4: RMSNorm*(1+scale)->bf16 rows.
__global__ __launch_bounds__(256) void prep(const float* __restrict__ W0, u16* __restrict__ T0,
                                            const float* __restrict__ W1, u16* __restrict__ T1,
                                            const float* __restrict__ W2, u16* __restrict__ T2,
                                            const float* __restrict__ W3, u16* __restrict__ T3,
                                            const float* __restrict__ x, const float* __restrict__ scale_x,
                                            const float* __restrict__ y, const float* __restrict__ scale_y,
                                            u16* __restrict__ xm, u16* __restrict__ ym) {
  __shared__ float t[32][33];
  const int z = blockIdx.z;
  if (z < 4) {
    const float* in; u16* out; int K, N;
    switch (z) {
      case 0: in = W0; out = T0; K = 1536; N = 4608; break;
      case 1: in = W1; out = T1; K = 768;  N = 4608; break;
      case 2: in = W2; out = T2; K = 1536; N = 1536; break;
      default: in = W3; out = T3; K = 1536; N = 768; break;
    }
    const int n0 = blockIdx.x * 32, k0 = blockIdx.y * 32;
    if (n0 >= N || k0 >= K) return;
    const int tx = threadIdx.x, ty = threadIdx.y;   // 32 x 8
#pragma unroll
    for (int i = 0; i < 32; i += 8)
      t[ty + i][tx] = in[(size_t)(k0 + ty + i) * N + n0 + tx];
    __syncthreads();
#pragma unroll
    for (int i = 0; i < 32; i += 8)
      out[(size_t)(n0 + ty + i) * K + k0 + tx] = f2bf(t[tx][ty + i]);
  } else {
    const int row = blockIdx.y * 144 + blockIdx.x;
    if (row >= 2304) return;
    const int tid = threadIdx.y * 32 + threadIdx.x;
    const float* xr; const float* sc; u16* dst; int D;
    if (row < 2048) { D = 1536; xr = x + (size_t)row * D; sc = scale_x; dst = xm + (size_t)row * D; }
    else { D = 768; xr = y + (size_t)(row - 2048) * D; sc = scale_y; dst = ym + (size_t)(row - 2048) * D; }
    float ss = 0.f;
    for (int c = tid; c < D; c += 256) { float v = xr[c]; ss += v * v; }
    for (int off = 32; off > 0; off >>= 1) ss += __shfl_down(ss, off);
    __shared__ float red[4];
    if ((tid & 63) == 0) red[tid >> 6] = ss;
    __syncthreads();
    const float tot = red[0] + red[1] + red[2] + red[3];
    const float r = rsqrtf(tot / (float)D + 1e-6f);
    for (int c = tid; c < D; c += 256)
      dst[c] = f2bf(xr[c] * r * (1.0f + sc[c]));
  }
}

// ---------------- dual bf16 MFMA GEMM (global_load_lds staging); z picks problem ----------------
// C(MxN) = A(MxK) * BT(NxK)^T + bias. M%128==0, N%128==0, K%32==0.
template <bool BOUT>
__global__ __launch_bounds__(256) void gemm2(const u16* __restrict__ A0, const u16* __restrict__ BT0,
                                             const float* __restrict__ bias0, void* __restrict__ C0,
                                             int M0, int N0, int K0,
                                             const u16* __restrict__ A1, const u16* __restrict__ BT1,
                                             const float* __restrict__ bias1, void* __restrict__ C1,
                                             int M1, int N1, int K1) {
  const u16 *A, *BT; const float* bias; void* Cout; int M, N, K;
  if (blockIdx.z == 0) { A = A0; BT = BT0; bias = bias0; Cout = C0; M = M0; N = N0; K = K0; }
  else { A = A1; BT = BT1; bias = bias1; Cout = C1; M = M1; N = N1; K = K1; }
  const int bm = blockIdx.y * 128, bn = blockIdx.x * 128;
  if (bm >= M || bn >= N) return;

  __shared__ __align__(16) u16 As[128 * 32];
  __shared__ __align__(16) u16 Bs[128 * 32];
  const int tid = threadIdx.x;
  const int lane = tid & 63, wave = tid >> 6;
  const int wm = (wave & 1) * 64, wn = (wave >> 1) * 64;
  const int row16 = lane & 15, quad = lane >> 4;

  floatx4 acc[4][4] = {};
  const int r0 = lane >> 2, c4 = (lane & 3) * 8;
  const u16* Ag0 = A + (size_t)(bm + wave * 16 + r0) * K + c4;
  const u16* Ag1 = A + (size_t)(bm + (wave + 4) * 16 + r0) * K + c4;
  const u16* Bg0 = BT + (size_t)(bn + wave * 16 + r0) * K + c4;
  const u16* Bg1 = BT + (size_t)(bn + (wave + 4) * 16 + r0) * K + c4;
  u16* As0 = As + wave * 512; u16* As1 = As + (wave + 4) * 512;
  u16* Bs0 = Bs + wave * 512; u16* Bs1 = Bs + (wave + 4) * 512;

  for (int k0 = 0; k0 < K; k0 += 32) {
    GLD16(Ag0 + k0, As0);
    GLD16(Ag1 + k0, As1);
    GLD16(Bg0 + k0, Bs0);
    GLD16(Bg1 + k0, Bs1);
    __syncthreads();
    short8 af[4], bf[4];
#pragma unroll
    for (int i = 0; i < 4; i++) {
      af[i] = *(const short8*)&As[(wm + i * 16 + row16) * 32 + quad * 8];
      bf[i] = *(const short8*)&Bs[(wn + i * 16 + row16) * 32 + quad * 8];
    }
#pragma unroll
    for (int mi = 0; mi < 4; mi++)
#pragma unroll
      for (int ni = 0; ni < 4; ni++)
        acc[mi][ni] = __builtin_amdgcn_mfma_f32_16x16x32_bf16(af[mi], bf[ni], acc[mi][ni], 0, 0, 0);
    __syncthreads();
  }
#pragma unroll
  for (int mi = 0; mi < 4; mi++) {
#pragma unroll
    for (int ni = 0; ni < 4; ni++) {
      const int col = bn + wn + ni * 16 + row16;
      const float b = bias[col];
      const int row0 = bm + wm + mi * 16 + quad * 4;
#pragma unroll
      for (int r = 0; r < 4; r++) {
        const float v = acc[mi][ni][r] + b;
        if constexpr (BOUT)
          ((u16*)Cout)[(size_t)(row0 + r) * N + col] = f2bf(v);
        else
          ((float*)Cout)[(size_t)(row0 + r) * N + col] = v;
      }
    }
  }
}

// ---------------- per-head q/k RMSNorm + RoPE(x only); emit Q,K,V bf16 (H,S,D) ----------------
// Q folded with (1/sqrt(D)) * log2(e) so attention works in exp2 domain.
__global__ __launch_bounds__(128) void qkv_post(const u16* __restrict__ qkvx,
                                                const u16* __restrict__ qkvy,
                                                const float* __restrict__ qnwx, const float* __restrict__ knwx,
                                                const float* __restrict__ qnwy, const float* __restrict__ knwy,
                                                const float* __restrict__ rcos, const float* __restrict__ rsin,
                                                u16* __restrict__ Q, u16* __restrict__ Kb, u16* __restrict__ V) {
  const int s = blockIdx.x, h = blockIdx.y, d = threadIdx.x;
  const bool isx = s < 2048;
  const u16* base = isx ? (qkvx + (size_t)s * 4608) : (qkvy + (size_t)(s - 2048) * 4608);
  const float q = bf2f(base[h * 128 + d]);
  const float k = bf2f(base[1536 + h * 128 + d]);
  const u16 v = base[3072 + h * 128 + d];
  __shared__ float redq[2], redk[2];
  float sq = q * q, sk = k * k;
  for (int off = 32; off > 0; off >>= 1) { sq += __shfl_down(sq, off); sk += __shfl_down(sk, off); }
  const int lane = threadIdx.x & 63, w = threadIdx.x >> 6;
  if (lane == 0) { redq[w] = sq; redk[w] = sk; }
  __syncthreads();
  const float rq = rsqrtf((redq[0] + redq[1]) * (1.f / 128.f) + 1e-5f);
  const float rk = rsqrtf((redk[0] + redk[1]) * (1.f / 128.f) + 1e-5f);
  float qn = q * rq * (isx ? qnwx[d] : qnwy[d]);
  float kn = k * rk * (isx ? knwx[d] : knwy[d]);
  if (isx) {
    const int i = d >> 1;
    const float c = rcos[((size_t)s * 12 + h) * 64 + i];
    const float sn = rsin[((size_t)s * 12 + h) * 64 + i];
    const float qo = __shfl_xor(qn, 1);
    const float ko = __shfl_xor(kn, 1);
    qn = (d & 1) ? (qo * sn + qn * c) : (qn * c - qo * sn);
    kn = (d & 1) ? (ko * sn + kn * c) : (kn * c - ko * sn);
  }
  qn *= 0.12751737942f;  // (1/sqrt(128)) * log2(e)
  const size_t o = ((size_t)h * 2304 + s) * 128 + d;
  Q[o] = f2bf(qn);
  Kb[o] = f2bf(kn);
  V[o] = v;
}

// ---------------- per-head V (S,D) -> Vt (D,S) ----------------
__global__ __launch_bounds__(256) void vtrans(const u16* __restrict__ V, u16* __restrict__ Vt) {
  __shared__ u16 t[32][33];
  const int h = blockIdx.x, st = blockIdx.y * 32, dt = blockIdx.z * 32;
  const u16* Vh = V + (size_t)h * 2304 * 128;
  u16* Vth = Vt + (size_t)h * 128 * 2304;
  const int tx = threadIdx.x, ty = threadIdx.y;
#pragma unroll
  for (int i = 0; i < 32; i += 8)
    t[ty + i][tx] = Vh[(size_t)(st + ty + i) * 128 + dt + tx];
  __syncthreads();
#pragma unroll
  for (int i = 0; i < 32; i += 8)
    Vth[(size_t)(dt + ty + i) * 2304 + st + tx] = t[tx][ty + i];
}

// ---------------- flash attention: GLD16 swizzled staging, transposed scores, 4-way split-K ------
// Grid (36 q-tiles, 12 heads, 4 splits). 64 q/block (16/wave), 64-key tiles, 576 keys/split.
// LDS 40KB x 4 blocks = 160KB/CU; launch_bounds(256,4) for 4-block residency.
__global__ __launch_bounds__(256, 4) void attn(const u16* __restrict__ Q, const u16* __restrict__ Kb,
                                               const u16* __restrict__ Vt,
                                               u16* __restrict__ Opart,
                                               float* __restrict__ Mp, float* __restrict__ Lp) {
  const int h = blockIdx.y, split = blockIdx.z;
  const int q0 = blockIdx.x * 64;
  const int tid = threadIdx.x, lane = tid & 63, wave = tid >> 6;
  const int row16 = lane & 15, quad = lane >> 4;
  const u16* Qh = Q + (size_t)h * 2304 * 128;
  const u16* Kh = Kb + (size_t)h * 2304 * 128;
  const u16* Vh = Vt + (size_t)h * 128 * 2304;

  __shared__ __align__(16) u16 Ks[64 * 128];   // swizzled: 64 key-rows x 16 chunks
  __shared__ __align__(16) u16 Vs[128 * 64];   // swizzled: 128 d-rows x 8 chunks
  __shared__ __align__(16) u16 Ps[4][16 * 64]; // swizzled per-wave P (16 q x 64 keys)

  short8 qf[4];
  {
    const u16* qrow = Qh + (size_t)(q0 + wave * 16 + row16) * 128;
#pragma unroll
    for (int kk = 0; kk < 4; kk++) qf[kk] = *(const short8*)(qrow + kk * 32 + quad * 8);
  }
  floatx4 oacc[8] = {};
  float m_i = -1e30f, l_i = 0.f;   // per-lane: q-column = row16

  int krow[4], kcol[4], vrow[4], vcol[4];
#pragma unroll
  for (int i = 0; i < 4; i++) {
    const int j = i * 4 + wave;
    krow[i] = j * 4 + (lane >> 4);            // key row 0..63
    kcol[i] = ((lane & 15) ^ (krow[i] & 7)) * 8;
    vrow[i] = j * 8 + (lane >> 3);            // d row 0..127
    vcol[i] = ((lane & 7) ^ (vrow[i] & 7)) * 8;
  }
  const int sw = row16 & 7;
  const int kbeg = split * 576, kend = kbeg + 576;

  for (int kt = kbeg; kt < kend; kt += 64) {
    __syncthreads();
#pragma unroll
    for (int i = 0; i < 4; i++) {
      GLD16(Kh + (size_t)(kt + krow[i]) * 128 + kcol[i], Ks + (i * 4 + wave) * 512);
      GLD16(Vh + (size_t)vrow[i] * 2304 + kt + vcol[i], Vs + (i * 4 + wave) * 512);
    }
    __syncthreads();

    // S^T: sacc[mk] covers keys mk*16+quad*4+r, q-col = row16
    floatx4 sacc[4] = {};
#pragma unroll
    for (int mk = 0; mk < 4; mk++) {
#pragma unroll
      for (int kk = 0; kk < 4; kk++) {
        const int c = (4 * kk + quad) ^ sw;
        const short8 kfrag = *(const short8*)&Ks[(mk * 16 + row16) * 128 + c * 8];
        sacc[mk] = __builtin_amdgcn_mfma_f32_16x16x32_bf16(kfrag, qf[kk], sacc[mk], 0, 0, 0);
      }
    }
    // online softmax: 16 in-lane scores + 2 cross-quad shuffles
    float mx = sacc[0][0];
#pragma unroll
    for (int mk = 0; mk < 4; mk++)
#pragma unroll
      for (int r = 0; r < 4; r++) mx = fmaxf(mx, sacc[mk][r]);
    mx = fmaxf(mx, __shfl_xor(mx, 16));
    mx = fmaxf(mx, __shfl_xor(mx, 32));
    const float mnew = fmaxf(m_i, mx);
    if (__any(mnew > m_i)) {   // wave-uniform rescale skip
      const float alpha = exp2f(m_i - mnew);
      m_i = mnew;
      const float a0 = __shfl(alpha, quad * 4 + 0);
      const float a1 = __shfl(alpha, quad * 4 + 1);
      const float a2 = __shfl(alpha, quad * 4 + 2);
      const float a3 = __shfl(alpha, quad * 4 + 3);
#pragma unroll
      for (int nd = 0; nd < 8; nd++) {
        oacc[nd][0] *= a0; oacc[nd][1] *= a1; oacc[nd][2] *= a2; oacc[nd][3] *= a3;
      }
      l_i *= alpha;
    }
    float s = 0.f;
#pragma unroll
    for (int mk = 0; mk < 4; mk++) {
#pragma unroll
      for (int r = 0; r < 4; r++) {
        const float p = exp2f(sacc[mk][r] - m_i);
        sacc[mk][r] = p;
        s += p;
      }
    }
    s += __shfl_xor(s, 16);
    s += __shfl_xor(s, 32);
    l_i += s;

    // P -> per-wave swizzled LDS via perm-packed bf16 (conflict-free b64 writes)
#pragma unroll
    for (int mk = 0; mk < 4; mk++) {
      const int subp = (4 * mk + quad) ^ (sw << 1);
      uint2 pk;
      pk.x = pack_bf2(sacc[mk][0], sacc[mk][1]);
      pk.y = pack_bf2(sacc[mk][2], sacc[mk][3]);
      *(uint2*)&Ps[wave][row16 * 64 + subp * 4] = pk;
    }
    const int pc0 = quad ^ sw, pc1 = (4 + quad) ^ sw;
    const short8 pf0 = *(const short8*)&Ps[wave][row16 * 64 + pc0 * 8];
    const short8 pf1 = *(const short8*)&Ps[wave][row16 * 64 + pc1 * 8];
#pragma unroll
    for (int nd = 0; nd < 8; nd++) {
      const short8 vf0 = *(const short8*)&Vs[(nd * 16 + row16) * 64 + pc0 * 8];
      const short8 vf1 = *(const short8*)&Vs[(nd * 16 + row16) * 64 + pc1 * 8];
      oacc[nd] = __builtin_amdgcn_mfma_f32_16x16x32_bf16(pf0, vf0, oacc[nd], 0, 0, 0);
      oacc[nd] = __builtin_amdgcn_mfma_f32_16x16x32_bf16(pf1, vf1, oacc[nd], 0, 0, 0);
    }
  }
  const size_t base = (size_t)(split * 12 + h) * 2304 + q0 + wave * 16;
#pragma unroll
  for (int nd = 0; nd < 8; nd++)
#pragma unroll
    for (int r = 0; r < 4; r++)
      Opart[(base + quad * 4 + r) * 128 + nd * 16 + row16] = f2bf(oacc[nd][r]);
  if (lane < 16) { Mp[base + lane] = m_i; Lp[base + lane] = l_i; }
}

// ---------------- combine 4 splits (bf16 partials) -> attnout bf16 (S, 1536) ----------------
__global__ __launch_bounds__(256) void attn_combine(const u16* __restrict__ Opart,
                                                    const float* __restrict__ Mp,
                                                    const float* __restrict__ Lp,
                                                    u16* __restrict__ attnout) {
  const int idx = blockIdx.x * 256 + threadIdx.x;   // one per 4 output elems
  const int dd = (idx & 31) * 4;
  const int hq = idx >> 5;
  const int h = hq % 12, q = hq / 12;
  size_t b[4]; float ms[4], ls[4];
  float m = -1e30f;
#pragma unroll
  for (int s = 0; s < 4; s++) {
    b[s] = (size_t)(s * 12 + h) * 2304 + q;
    ms[s] = Mp[b[s]]; ls[s] = Lp[b[s]];
    m = fmaxf(m, ms[s]);
  }
  float w[4], denom = 0.f;
#pragma unroll
  for (int s = 0; s < 4; s++) { w[s] = exp2f(ms[s] - m); denom += ls[s] * w[s]; }
  const float inv = 1.0f / denom;
  float ox = 0.f, oy = 0.f, oz = 0.f, ow = 0.f;
#pragma unroll
  for (int s = 0; s < 4; s++) {
    const short4v o = *(const short4v*)&Opart[b[s] * 128 + dd];
    ox += bf2f((u16)o[0]) * w[s]; oy += bf2f((u16)o[1]) * w[s];
    oz += bf2f((u16)o[2]) * w[s]; ow += bf2f((u16)o[3]) * w[s];
  }
  short4v out;
  out[0] = (short)f2bf(ox * inv);
  out[1] = (short)f2bf(oy * inv);
  out[2] = (short)f2bf(oz * inv);
  out[3] = (short)f2bf(ow * inv);
  *(short4v*)&attnout[(size_t)idx * 4] = out;
}

// ---------------- launch ----------------
extern "C" void kernel_launch(void* const* d_in, const int* in_sizes, int n_in,
                              void* d_out, int out_size, void* d_ws, size_t ws_size,
                              hipStream_t stream) {
  const float* x        = (const float*)d_in[0];
  const float* y        = (const float*)d_in[1];
  const float* scale_x  = (const float*)d_in[2];
  const float* scale_y  = (const float*)d_in[3];
  const float* rope_cos = (const float*)d_in[4];
  const float* rope_sin = (const float*)d_in[5];
  const float* Wqkv_x   = (const float*)d_in[6];
  const float* bqkv_x   = (const float*)d_in[7];
  const float* Wqkv_y   = (const float*)d_in[8];
  const float* bqkv_y   = (const float*)d_in[9];
  const float* qnwx     = (const float*)d_in[10];
  const float* knwx     = (const float*)d_in[11];
  const float* qnwy     = (const float*)d_in[12];
  const float* knwy     = (const float*)d_in[13];
  const float* Wproj_x  = (const float*)d_in[14];
  const float* bproj_x  = (const float*)d_in[15];
  const float* Wproj_y  = (const float*)d_in[16];
  const float* bproj_y  = (const float*)d_in[17];
  float* out = (float*)d_out;

  char* ws = (char*)d_ws;
  size_t off = 0;
  auto take = [&](size_t bytes) { char* p = ws + off; off += (bytes + 255) & ~(size_t)255; return p; };
  u16* WqkvxT  = (u16*)take((size_t)4608 * 1536 * 2);
  u16* WqkvyT  = (u16*)take((size_t)4608 * 768 * 2);
  u16* WprojxT = (u16*)take((size_t)1536 * 1536 * 2);
  u16* WprojyT = (u16*)take((size_t)768 * 1536 * 2);
  u16* xm      = (u16*)take((size_t)2048 * 1536 * 2);
  u16* ym      = (u16*)take((size_t)256 * 768 * 2);
  u16* qkvx    = (u16*)take((size_t)2048 * 4608 * 2);
  u16* qkvy    = (u16*)take((size_t)256 * 4608 * 2);
  u16* Qb      = (u16*)take((size_t)12 * 2304 * 128 * 2);
  u16* Kb      = (u16*)take((size_t)12 * 2304 * 128 * 2);
  u16* Vb      = (u16*)take((size_t)12 * 2304 * 128 * 2);
  u16* Vt      = (u16*)take((size_t)12 * 128 * 2304 * 2);
  u16* attnout = (u16*)take((size_t)2304 * 1536 * 2);
  u16* Opart   = (u16*)take((size_t)4 * 12 * 2304 * 128 * 2);
  float* Mp    = (float*)take((size_t)4 * 12 * 2304 * 4);
  float* Lp    = (float*)take((size_t)4 * 12 * 2304 * 4);

  prep<<<dim3(144, 48, 5), dim3(32, 8), 0, stream>>>(Wqkv_x, WqkvxT, Wqkv_y, WqkvyT,
                                                     Wproj_x, WprojxT, Wproj_y, WprojyT,
                                                     x, scale_x, y, scale_y, xm, ym);

  gemm2<true><<<dim3(36, 16, 2), 256, 0, stream>>>(xm, WqkvxT, bqkv_x, qkvx, 2048, 4608, 1536,
                                                   ym, WqkvyT, bqkv_y, qkvy, 256, 4608, 768);

  qkv_post<<<dim3(2304, 12), 128, 0, stream>>>(qkvx, qkvy, qnwx, knwx, qnwy, knwy,
                                               rope_cos, rope_sin, Qb, Kb, Vb);
  vtrans<<<dim3(12, 2304 / 32, 128 / 32), dim3(32, 8), 0, stream>>>(Vb, Vt);

  attn<<<dim3(2304 / 64, 12, 4), 256, 0, stream>>>(Qb, Kb, Vt, Opart, Mp, Lp);
  attn_combine<<<(2304 * 1536 / 4) / 256, 256, 0, stream>>>(Opart, Mp, Lp, attnout);

  gemm2<false><<<dim3(12, 16, 2), 256, 0, stream>>>(attnout, WprojxT, bproj_x, out, 2048, 1536, 1536,
                                                    attnout + (size_t)2048 * 1536, WprojyT, bproj_y,
                                                    out + (size_t)2048 * 1536, 256, 768, 1536);
  (void)in_sizes; (void)n_in; (void)out_size; (void)ws_size;
}